// Round 13
// baseline (463.406 us; speedup 1.0000x reference)
//
#include <hip/hip_runtime.h>
#include <cstdint>
#include <cstddef>

namespace {
constexpr int B = 256, L = 200, H = 128, V = 50000, TK = 20;
constexpr int NT = 1563;                   // ceil(V/32)
constexpr float NEGV = -1e10f;
}

using bf16x8 = __attribute__((ext_vector_type(8))) short;
using s16x8  = __attribute__((ext_vector_type(8))) short;
using f32x16 = __attribute__((ext_vector_type(16))) float;

__device__ inline unsigned short f2bf(float f) {
  unsigned int u = __float_as_uint(f);
  unsigned int r = (u + 0x7fffu + ((u >> 16) & 1u)) >> 16;   // RNE
  return (unsigned short)r;
}

// ---- 16-lane-group DPP reductions ------------------------------------------
#define DPP_QUAD_XOR1 0xB1
#define DPP_QUAD_XOR2 0x4E
#define DPP_ROW_HMIRR 0x141
#define DPP_ROW_MIRR  0x140

template <int CTRL>
__device__ inline unsigned dpp16_max_step(unsigned v) {
  unsigned t = (unsigned)__builtin_amdgcn_update_dpp(0, (int)v, CTRL, 0xF, 0xF, true);
  return v > t ? v : t;
}
__device__ inline unsigned grp16_max(unsigned v) {
  v = dpp16_max_step<DPP_QUAD_XOR1>(v);
  v = dpp16_max_step<DPP_QUAD_XOR2>(v);
  v = dpp16_max_step<DPP_ROW_HMIRR>(v);
  v = dpp16_max_step<DPP_ROW_MIRR>(v);
  return v;                                   // uniform within each 16-group
}
template <int CTRL>
__device__ inline float dpp16_add_step(float v) {
  int t = __builtin_amdgcn_update_dpp(0, __float_as_int(v), CTRL, 0xF, 0xF, true);
  return v + __int_as_float(t);
}
__device__ inline float grp16_sum(float v) {
  v = dpp16_add_step<DPP_QUAD_XOR1>(v);
  v = dpp16_add_step<DPP_QUAD_XOR2>(v);
  v = dpp16_add_step<DPP_ROW_HMIRR>(v);
  v = dpp16_add_step<DPP_ROW_MIRR>(v);
  return v;
}

__device__ inline unsigned f2key(float f) {        // order-preserving, bijective
  unsigned b = __float_as_uint(f);
  unsigned m = (unsigned)((int)b >> 31);
  return b ^ (m | 0x80000000u);
}
__device__ inline float key2f(unsigned u) {
  unsigned b = (u & 0x80000000u) ? (u & 0x7fffffffu) : ~u;
  return __uint_as_float(b);
}

// ---- embed + norm + frag-linear bf16 hi/lo staging --------------------------
__global__ __launch_bounds__(256) void k_embed(const int* __restrict__ seq,
                                               const int* __restrict__ rev,
                                               const float* __restrict__ emb,
                                               const float* __restrict__ wnoise,
                                               float* __restrict__ hidden,
                                               float* __restrict__ nrm,
                                               s16x8* __restrict__ hbh,
                                               s16x8* __restrict__ hbl,
                                               s16x8* __restrict__ wnh,
                                               s16x8* __restrict__ wnl) {
  int b = blockIdx.x / 7, lt = blockIdx.x % 7;
  int t = threadIdx.x;
  int r = t >> 3, c2 = t & 7;                 // row-in-tile, 16-elem h-chunk
  int l = lt * 32 + r;
  bool valid = l < L;
  float vv[16], wv[16];
  if (valid) {
    int row = b * L + l;
    int tok = seq[row];
    const float4* ep = (const float4*)&emb[(size_t)tok * H + c2 * 16];
    const float4* wp = (const float4*)&wnoise[(size_t)rev[row] * H + c2 * 16];
#pragma unroll
    for (int i = 0; i < 4; ++i) {
      float4 x = ep[i];
      vv[i * 4 + 0] = x.x; vv[i * 4 + 1] = x.y; vv[i * 4 + 2] = x.z; vv[i * 4 + 3] = x.w;
      float4 y = wp[i];
      wv[i * 4 + 0] = y.x; wv[i * 4 + 1] = y.y; wv[i * 4 + 2] = y.z; wv[i * 4 + 3] = y.w;
    }
  } else {
#pragma unroll
    for (int i = 0; i < 16; ++i) { vv[i] = 0.f; wv[i] = 0.f; }
  }
  if (valid) {
    int row = b * L + l;
#pragma unroll
    for (int i = 0; i < 4; ++i)
      *(float4*)&hidden[(size_t)row * H + c2 * 16 + i * 4] =
          make_float4(vv[i * 4], vv[i * 4 + 1], vv[i * 4 + 2], vv[i * 4 + 3]);
    float s = 0.f;
#pragma unroll
    for (int i = 0; i < 16; ++i) s += vv[i] * vv[i];
    s += __shfl_down(s, 4, 8);
    s += __shfl_down(s, 2, 8);
    s += __shfl_down(s, 1, 8);
    if (c2 == 0) nrm[row] = sqrtf(s);
  }
  s16x8 h0, h1, l0, l1, w0, w1, x0, x1;
#pragma unroll
  for (int i = 0; i < 8; ++i) {
    unsigned short hi = f2bf(vv[i]);
    h0[i] = (short)hi;
    l0[i] = (short)f2bf(vv[i] - __uint_as_float((unsigned)hi << 16));
    unsigned short wh = f2bf(wv[i]);
    w0[i] = (short)wh;
    x0[i] = (short)f2bf(wv[i] - __uint_as_float((unsigned)wh << 16));
  }
#pragma unroll
  for (int i = 0; i < 8; ++i) {
    unsigned short hi = f2bf(vv[8 + i]);
    h1[i] = (short)hi;
    l1[i] = (short)f2bf(vv[8 + i] - __uint_as_float((unsigned)hi << 16));
    unsigned short wh = f2bf(wv[8 + i]);
    w1[i] = (short)wh;
    x1[i] = (short)f2bf(wv[8 + i] - __uint_as_float((unsigned)wh << 16));
  }
  size_t fi0 = ((size_t)(b * 7 + lt) * 8 + c2) * 64 + r;   // kh=0
  size_t fi1 = fi0 + 32;                                   // kh=1
  hbh[fi0] = h0; hbh[fi1] = h1;
  hbl[fi0] = l0; hbl[fi1] = l1;
  wnh[fi0] = w0; wnh[fi1] = w1;
  wnl[fi0] = x0; wnl[fi1] = x1;
}

// ------------------------------------------ slen, zero_layer (into ecacc), e_s
__global__ __launch_bounds__(512) void k_init(const int* __restrict__ lengths,
                                              const float* __restrict__ hidden,
                                              float* __restrict__ ecacc,
                                              float* __restrict__ e_s) {
  int b = blockIdx.x, tid = threadIdx.x;
  __shared__ float part[4][128];
  __shared__ int wcnt[8];
  __shared__ int s_slen;
  int c = (tid < L && lengths[b * L + tid] > 0) ? 1 : 0;
  for (int o = 32; o > 0; o >>= 1) c += __shfl_down(c, o, 64);
  if ((tid & 63) == 0) wcnt[tid >> 6] = c;
  __syncthreads();
  if (tid == 0) {
    int s = 0;
#pragma unroll
    for (int i = 0; i < 8; ++i) s += wcnt[i];
    s_slen = s;
  }
  int h = tid & 127, seg = tid >> 7;
  float s = 0.f;
  for (int l = seg; l < L; l += 4) s += hidden[(size_t)(b * L + l) * H + h];
  part[seg][h] = s;
  __syncthreads();
  if (tid < 128) {
    float tot = part[0][h] + part[1][h] + part[2][h] + part[3][h];
    int slen = s_slen;
    ecacc[b * H + h] = tot / (float)slen;
    e_s[b * H + h] = hidden[(size_t)(b * L + slen - 1) * H + h];
  }
}

// ---- S0 = cosine sim (+diag), WS = softplus(hidden·wn), bf16x3 split MFMA ---
// one 32x32 mtile per wave; grid = 8 XCD * 32 b * 7 lt * 2 half
__global__ __launch_bounds__(256) void k_simws(const s16x8* __restrict__ hbh,
                                               const s16x8* __restrict__ hbl,
                                               const s16x8* __restrict__ wnh,
                                               const s16x8* __restrict__ wnl,
                                               const float* __restrict__ nrm,
                                               const int* __restrict__ rev,
                                               const float* __restrict__ cluster,
                                               float* __restrict__ S0,
                                               float* __restrict__ WS) {
  int orig = blockIdx.x;                     // 0..3583
  int xcd = orig & 7, slot = orig >> 3;      // slot 0..447
  int b = xcd * 32 + slot / 14;
  int rem = slot % 14;
  int lt = rem >> 1, half = rem & 1;
  int wid = threadIdx.x >> 6, lane = threadIdx.x & 63;
  int mt = half * 4 + wid;                   // 0..7
  if (mt > 6) return;                        // one idle wave in odd halves
  int lr = lane & 31, kh = lane >> 5;
  size_t abase = ((size_t)(b * 7 + lt) * 8) * 64 + lane;
  bf16x8 ah[8], al[8];
#pragma unroll
  for (int ks = 0; ks < 8; ++ks) {
    ah[ks] = (bf16x8)hbh[abase + ks * 64];
    al[ks] = (bf16x8)hbl[abase + ks * 64];
  }
  size_t bbase = ((size_t)(b * 7 + mt) * 8) * 64 + lane;
  f32x16 accs = {}, accw = {};
#pragma unroll
  for (int ks = 0; ks < 8; ++ks) {
    bf16x8 bhh = (bf16x8)hbh[bbase + ks * 64];
    bf16x8 bhl = (bf16x8)hbl[bbase + ks * 64];
    bf16x8 bwh = (bf16x8)wnh[bbase + ks * 64];
    bf16x8 bwl = (bf16x8)wnl[bbase + ks * 64];
    accs = __builtin_amdgcn_mfma_f32_32x32x16_bf16(ah[ks], bhh, accs, 0, 0, 0);
    accs = __builtin_amdgcn_mfma_f32_32x32x16_bf16(ah[ks], bhl, accs, 0, 0, 0);
    accs = __builtin_amdgcn_mfma_f32_32x32x16_bf16(al[ks], bhh, accs, 0, 0, 0);
    accw = __builtin_amdgcn_mfma_f32_32x32x16_bf16(ah[ks], bwh, accw, 0, 0, 0);
    accw = __builtin_amdgcn_mfma_f32_32x32x16_bf16(ah[ks], bwl, accw, 0, 0, 0);
    accw = __builtin_amdgcn_mfma_f32_32x32x16_bf16(al[ks], bwh, accw, 0, 0, 0);
  }
  int m = mt * 32 + lr;
  if (m < L) {
    float nm = nrm[b * L + m];
#pragma unroll
    for (int r = 0; r < 16; ++r) {
      int row = lt * 32 + (r & 3) + 8 * (r >> 2) + 4 * kh;
      if (row < L) {
        float nl = nrm[b * L + row];
        float s0 = accs[r] * __builtin_amdgcn_rcpf(nl * nm + 1e-6f);
        if (row == m) s0 += cluster[rev[b * L + row]];
        size_t o = (size_t)(b * L + row) * L + m;
        S0[o] = s0;
        float x = accw[r];
        WS[o] = (x > 1.f) ? x : __logf(1.f + __expf(x));
      }
    }
  }
}

// ------- per row-pair: msim in regs, candidate-cached top-K, 2 interleaved
// argmax chains per 16-lane group (8 rows/wave, 32 rows/block, grid B*7)
__global__ __launch_bounds__(256) void k_rowpass(const float* __restrict__ S0,
                                                 const float* __restrict__ WS,
                                                 const float* __restrict__ coff_i,
                                                 const int* __restrict__ lengths,
                                                 float* __restrict__ P,
                                                 unsigned char* __restrict__ ET) {
  __shared__ unsigned klds[256 * 27];        // 26 used, stride 27 (bank-friendly)
  int wid = threadIdx.x >> 6, lane = threadIdx.x & 63;
  int g = lane >> 4, q = lane & 15;
  int bb = blockIdx.x / 7, blk = blockIdx.x % 7;
  int g16 = wid * 4 + g;                     // 0..15
  int lA = blk * 32 + g16 * 2, lB = lA + 1;
  bool lvA = lA < L, lvB = lB < L;
  int lrowA = bb * L + (lvA ? lA : 0);
  int lrowB = bb * L + (lvB ? lB : 0);
  bool mA = lvA && (lengths[lrowA] > 0);
  bool mB = lvB && (lengths[lrowB] > 0);
  size_t baseA = (size_t)lrowA * L, baseB = (size_t)lrowB * L;
  int kbA = threadIdx.x * 27, kbB = kbA + 13;
  float valA[13], valB[13]; unsigned vmA = 0, vmB = 0;
  unsigned a0 = 0, a1 = 0, a2 = 0; int aj0 = 0, aj1 = 0, aj2 = 0;
  unsigned c0 = 0, c1 = 0, c2 = 0; int cj0 = 0, cj1 = 0, cj2 = 0;
#pragma unroll
  for (int j = 0; j < 13; ++j) {
    int m = q + 16 * j;
    bool colOk = (m < L) && (lengths[bb * L + m] > 0);
    bool okA = mA && colOk, okB = mB && colOk;
    float vA = 0.f, vB = 0.f;
    if (okA) vA = S0[baseA + m] + coff_i[baseA + m] * WS[baseA + m];
    if (okB) vB = S0[baseB + m] + coff_i[baseB + m] * WS[baseB + m];
    valA[j] = vA; valB[j] = vB;
    unsigned kA = okA ? f2key(vA) : 0u;
    unsigned kB = okB ? f2key(vB) : 0u;
    vmA |= okA ? (1u << j) : 0u;
    vmB |= okB ? (1u << j) : 0u;
    klds[kbA + j] = kA;
    klds[kbB + j] = kB;
    // per-lane sorted top-3 (strict > keeps lowest j on ties = lowest m)
    if (kA > a0)      { a2 = a1; aj2 = aj1; a1 = a0; aj1 = aj0; a0 = kA; aj0 = j; }
    else if (kA > a1) { a2 = a1; aj2 = aj1; a1 = kA; aj1 = j; }
    else if (kA > a2) { a2 = kA; aj2 = j; }
    if (kB > c0)      { c2 = c1; cj2 = cj1; c1 = c0; cj1 = cj0; c0 = kB; cj0 = j; }
    else if (kB > c1) { c2 = c1; cj2 = cj1; c1 = kB; cj1 = j; }
    else if (kB > c2) { c2 = kB; cj2 = j; }
  }
  unsigned ccA = a0; int cjA = aj0; int consA = 0;
  unsigned ccB = c0; int cjB = cj0; int consB = 0;
  unsigned MuA = 0u, MuB = 0u;
  for (int t = 0; t < TK; ++t) {
    unsigned gmA = grp16_max(ccA);
    unsigned gmB = grp16_max(ccB);
    if (t == 0) { MuA = gmA; MuB = gmB; }
    if (__all((gmA | gmB) == 0u)) break;     // all 8 rows of wave exhausted
    unsigned long long balA = __ballot(ccA == gmA && gmA != 0u);
    unsigned long long balB = __ballot(ccB == gmB && gmB != 0u);
    unsigned long long grpm = 0xFFFFull << (g * 16);
    unsigned long long mineA = balA & grpm;
    unsigned long long mineB = balB & grpm;
    int ownA = mineA ? (int)__builtin_ctzll(mineA) : -1;
    int ownB = mineB ? (int)__builtin_ctzll(mineB) : -1;
    if (lane == ownA) {                      // lowest lane of group (tie ok)
      int m = q + 16 * cjA;
      ET[((size_t)bb * L + m) * L + lA] = 1;
      klds[kbA + cjA] = 0u;
      ++consA;
      if (consA == 1)      { ccA = a1; cjA = aj1; }
      else if (consA == 2) { ccA = a2; cjA = aj2; }
      else {
        unsigned x = 0; int xj = 0;
#pragma unroll
        for (int j = 0; j < 13; ++j) {
          unsigned k2 = klds[kbA + j];
          if (k2 > x) { x = k2; xj = j; }
        }
        ccA = x; cjA = xj;
      }
    }
    if (lane == ownB) {
      int m = q + 16 * cjB;
      ET[((size_t)bb * L + m) * L + lB] = 1;
      klds[kbB + cjB] = 0u;
      ++consB;
      if (consB == 1)      { ccB = c1; cjB = cj1; }
      else if (consB == 2) { ccB = c2; cjB = cj2; }
      else {
        unsigned x = 0; int xj = 0;
#pragma unroll
        for (int j = 0; j < 13; ++j) {
          unsigned k2 = klds[kbB + j];
          if (k2 > x) { x = k2; xj = j; }
        }
        ccB = x; cjB = xj;
      }
    }
  }
  // softmax over both rows (invalid entries contribute exactly 0)
  float MA = key2f(MuA), MB = key2f(MuB);
  float eA[13], eB[13]; float sA = 0.f, sB = 0.f;
#pragma unroll
  for (int j = 0; j < 13; ++j) {
    float evA = ((vmA >> j) & 1u) ? __expf(valA[j] - MA) : 0.f;
    float evB = ((vmB >> j) & 1u) ? __expf(valB[j] - MB) : 0.f;
    eA[j] = evA; sA += evA;
    eB[j] = evB; sB += evB;
  }
  sA = grp16_sum(sA);
  sB = grp16_sum(sB);
  float invA = (sA > 0.f) ? __builtin_amdgcn_rcpf(sA) : 0.f;
  float invB = (sB > 0.f) ? __builtin_amdgcn_rcpf(sB) : 0.f;
#pragma unroll
  for (int j = 0; j < 13; ++j) {
    int m = q + 16 * j;
    if (m < L) {
      if (lvA) P[baseA + m] = eA[j] * invA;
      if (lvB) P[baseB + m] = eB[j] * invB;
    }
  }
}

// ---- FUSED compact+update: ssm row -> cmask + LDS edge list -> gather -------
// 512 threads, 4 rows/block: waves 0-3 compact row 4*bid+wv (waves 4-7 wait);
// then all 512 threads gather (128 thr/row).
__global__ __launch_bounds__(512) void k_gather(const float* __restrict__ P,
                                                const unsigned char* __restrict__ ET,
                                                const float* __restrict__ hidden,
                                                float* __restrict__ cmask,
                                                float* __restrict__ upd) {
  __shared__ float wls[4][224];
  __shared__ unsigned char ils[4][224];
  __shared__ int s_cnt[4];
  int wv = threadIdx.x >> 6, lane = threadIdx.x & 63;
  if (wv < 4) {                              // ONLY 4 compaction waves (fix: was OOB)
    int rowW = blockIdx.x * 4 + wv;
    size_t baseW = (size_t)rowW * L;
    float w[4]; float s = 0.f;
#pragma unroll
    for (int j = 0; j < 4; ++j) {
      int m = lane + 64 * j;
      float ww = 0.f;
      if (m < L) ww = P[baseW + m] * (float)ET[baseW + m];
      w[j] = ww; s += ww;
    }
    float ssum = s;
    for (int off = 1; off < 64; off <<= 1) ssum += __shfl_xor(ssum, off, 64);
    if (lane == 0) cmask[rowW] = ssum;
    int pos_base = 0;
#pragma unroll
    for (int j = 0; j < 4; ++j) {
      bool nz = (w[j] != 0.f);
      unsigned long long mk = __ballot(nz);
      int rank = __popcll(mk & ((1ull << lane) - 1ull));
      if (nz) {
        int pos = pos_base + rank;
        ils[wv][pos] = (unsigned char)(lane + 64 * j);
        wls[wv][pos] = w[j];
      }
      pos_base += (int)__popcll(mk);
    }
    if (lane == 0) s_cnt[wv] = pos_base;
    int padEnd = ((pos_base + TK - 1) / TK) * TK;   // zero-pad to 20-multiple
    for (int p = pos_base + lane; p < padEnd; p += 64) {
      ils[wv][p] = 0; wls[wv][p] = 0.f;
    }
  }
  __syncthreads();
  int half = threadIdx.x >> 7;               // 0..3 -> row in block
  int h = threadIdx.x & 127;
  int row = blockIdx.x * 4 + half;
  int b = row / L;
  int n = s_cnt[half];
  float acc = 0.f;
  for (int e0 = 0; e0 < n; e0 += TK) {
    float w[TK]; int m[TK];
#pragma unroll
    for (int e = 0; e < TK; ++e) { w[e] = wls[half][e0 + e]; m[e] = ils[half][e0 + e]; }
    float hv[TK];
#pragma unroll
    for (int e = 0; e < TK; ++e)
      hv[e] = hidden[(size_t)(b * L + m[e]) * H + h];
#pragma unroll
    for (int e = 0; e < TK; ++e)
      acc += w[e] * hv[e];                   // padded entries are exact zeros
  }
  upd[(size_t)row * H + h] = acc;
}

// -------------------------------------------- cmask /= max(||cmask||_2, 1e-12)
__global__ __launch_bounds__(64) void k_cnorm(float* __restrict__ cmask) {
  int b = blockIdx.x, lane = threadIdx.x;   // 64 threads
  float v[4]; float s = 0.f;
#pragma unroll
  for (int j = 0; j < 4; ++j) {
    int l = lane + 64 * j;
    float x = (l < L) ? cmask[b * L + l] : 0.f;
    v[j] = x; s += x * x;
  }
  for (int off = 1; off < 64; off <<= 1) s += __shfl_xor(s, off, 64);
  float inv = 1.f / fmaxf(sqrtf(s), 1e-12f);
#pragma unroll
  for (int j = 0; j < 4; ++j) {
    int l = lane + 64 * j;
    if (l < L) cmask[b * L + l] = v[j] * inv;
  }
}

// ----- FFN + residual + LN via bf16x3 MFMA, weighted by cmask, in-place ------
__global__ __launch_bounds__(256) void k_ffn(float* __restrict__ upd,
                                             const float* __restrict__ W1,
                                             const float* __restrict__ b1,
                                             const float* __restrict__ W2,
                                             const float* __restrict__ b2,
                                             const float* __restrict__ g,
                                             const float* __restrict__ beta,
                                             const float* __restrict__ cmask) {
  constexpr int AS = 136;                            // short stride (16B-aligned rows)
  __shared__ __align__(16) char smem[4 * 64 * AS * 2];  // 69632 B
  short* ahs = (short*)smem;                         // A hi  [64][AS]
  short* als = ahs + 64 * AS;                        // A lo
  short* f1h = (short*)(smem + 2 * 64 * AS * 2);     // feed1 hi
  short* f1l = f1h + 64 * AS;
  float (*ps)[132] = (float (*)[132])smem;           // aliases A (dead after GEMM1)
  __shared__ float mus[64], rsd[64];
  int row0 = blockIdx.x * 64;
  int tid = threadIdx.x;
  int wid = tid >> 6, lane = tid & 63;
  int lr = lane & 31, kh = lane >> 5;
  int n0 = wid * 32;
  int n = n0 + lr;
  // ---- stage upd -> bf16 hi/lo LDS ----
#pragma unroll
  for (int it = 0; it < 8; ++it) {
    int f = it * 256 + tid;
    int r = f >> 5, c4 = (f & 31) * 4;
    float4 v = *(const float4*)&upd[(size_t)(row0 + r) * H + c4];
    float vv[4] = {v.x, v.y, v.z, v.w};
    unsigned short hh[4]; short ll[4];
#pragma unroll
    for (int q2 = 0; q2 < 4; ++q2) {
      hh[q2] = f2bf(vv[q2]);
      ll[q2] = (short)f2bf(vv[q2] - __uint_as_float((unsigned)hh[q2] << 16));
    }
    uint2 ph = make_uint2((unsigned)hh[0] | ((unsigned)hh[1] << 16),
                          (unsigned)hh[2] | ((unsigned)hh[3] << 16));
    uint2 pl = make_uint2((unsigned short)ll[0] | ((unsigned)(unsigned short)ll[1] << 16),
                          (unsigned short)ll[2] | ((unsigned)(unsigned short)ll[3] << 16));
    *(uint2*)&ahs[r * AS + c4] = ph;
    *(uint2*)&als[r * AS + c4] = pl;
  }
  __syncthreads();
  // ---- W1 fragments ----
  bf16x8 wfh[8], wfl[8];
#pragma unroll
  for (int ks = 0; ks < 8; ++ks) {
#pragma unroll
    for (int i = 0; i < 8; ++i) {
      float w = W1[(size_t)(ks * 16 + kh * 8 + i) * H + n];
      unsigned short hi = f2bf(w);
      wfh[ks][i] = (short)hi;
      wfl[ks][i] = (short)f2bf(w - __uint_as_float((unsigned)hi << 16));
    }
  }
  // ---- GEMM1: feed1 = relu(upd @ W1 + b1) ----
  f32x16 acc0, acc1;
  {
    float bv = b1[n];
#pragma unroll
    for (int r = 0; r < 16; ++r) { acc0[r] = bv; acc1[r] = bv; }
  }
#pragma unroll
  for (int ks = 0; ks < 8; ++ks) {
    bf16x8 xh0 = *(const bf16x8*)&ahs[(0 * 32 + lr) * AS + ks * 16 + kh * 8];
    bf16x8 xl0 = *(const bf16x8*)&als[(0 * 32 + lr) * AS + ks * 16 + kh * 8];
    bf16x8 xh1 = *(const bf16x8*)&ahs[(1 * 32 + lr) * AS + ks * 16 + kh * 8];
    bf16x8 xl1 = *(const bf16x8*)&als[(1 * 32 + lr) * AS + ks * 16 + kh * 8];
    acc0 = __builtin_amdgcn_mfma_f32_32x32x16_bf16(xh0, wfh[ks], acc0, 0, 0, 0);
    acc0 = __builtin_amdgcn_mfma_f32_32x32x16_bf16(xl0, wfh[ks], acc0, 0, 0, 0);
    acc0 = __builtin_amdgcn_mfma_f32_32x32x16_bf16(xh0, wfl[ks], acc0, 0, 0, 0);
    acc1 = __builtin_amdgcn_mfma_f32_32x32x16_bf16(xh1, wfh[ks], acc1, 0, 0, 0);
    acc1 = __builtin_amdgcn_mfma_f32_32x32x16_bf16(xl1, wfh[ks], acc1, 0, 0, 0);
    acc1 = __builtin_amdgcn_mfma_f32_32x32x16_bf16(xh1, wfl[ks], acc1, 0, 0, 0);
  }
  // relu -> f1 hi/lo LDS (C layout: row=(r&3)+8*(r>>2)+4*kh, col=n)
#pragma unroll
  for (int r = 0; r < 16; ++r) {
    int crow = (r & 3) + 8 * (r >> 2) + 4 * kh;
    float f0 = fmaxf(acc0[r], 0.f);
    unsigned short h0 = f2bf(f0);
    f1h[crow * AS + n] = (short)h0;
    f1l[crow * AS + n] = (short)f2bf(f0 - __uint_as_float((unsigned)h0 << 16));
    float f1v = fmaxf(acc1[r], 0.f);
    unsigned short h1 = f2bf(f1v);
    f1h[(32 + crow) * AS + n] = (short)h1;
    f1l[(32 + crow) * AS + n] = (short)f2bf(f1v - __uint_as_float((unsigned)h1 << 16));
  }
  __syncthreads();                                    // f1 complete; A region dead
  // ---- W2 fragments ----
#pragma unroll
  for (int ks = 0; ks < 8; ++ks) {
#pragma unroll
    for (int i = 0; i < 8; ++i) {
      float w = W2[(size_t)(ks * 16 + kh * 8 + i) * H + n];
      unsigned short hi = f2bf(w);
      wfh[ks][i] = (short)hi;
      wfl[ks][i] = (short)f2bf(w - __uint_as_float((unsigned)hi << 16));
    }
  }
  // ---- GEMM2: pre = feed1 @ W2 + b2 + upd ----
  {
    float bv = b2[n];
#pragma unroll
    for (int r = 0; r < 16; ++r) { acc0[r] = bv; acc1[r] = bv; }
  }
#pragma unroll
  for (int ks = 0; ks < 8; ++ks) {
    bf16x8 xh0 = *(const bf16x8*)&f1h[(0 * 32 + lr) * AS + ks * 16 + kh * 8];
    bf16x8 xl0 = *(const bf16x8*)&f1l[(0 * 32 + lr) * AS + ks * 16 + kh * 8];
    bf16x8 xh1 = *(const bf16x8*)&f1h[(1 * 32 + lr) * AS + ks * 16 + kh * 8];
    bf16x8 xl1 = *(const bf16x8*)&f1l[(1 * 32 + lr) * AS + ks * 16 + kh * 8];
    acc0 = __builtin_amdgcn_mfma_f32_32x32x16_bf16(xh0, wfh[ks], acc0, 0, 0, 0);
    acc0 = __builtin_amdgcn_mfma_f32_32x32x16_bf16(xl0, wfh[ks], acc0, 0, 0, 0);
    acc0 = __builtin_amdgcn_mfma_f32_32x32x16_bf16(xh0, wfl[ks], acc0, 0, 0, 0);
    acc1 = __builtin_amdgcn_mfma_f32_32x32x16_bf16(xh1, wfh[ks], acc1, 0, 0, 0);
    acc1 = __builtin_amdgcn_mfma_f32_32x32x16_bf16(xl1, wfh[ks], acc1, 0, 0, 0);
    acc1 = __builtin_amdgcn_mfma_f32_32x32x16_bf16(xh1, wfl[ks], acc1, 0, 0, 0);
  }
  // residual + write ps (pre) — ps aliases A region (dead since barrier)
#pragma unroll
  for (int r = 0; r < 16; ++r) {
    int crow = (r & 3) + 8 * (r >> 2) + 4 * kh;
    float p0 = acc0[r] + upd[(size_t)(row0 + crow) * H + n];
    float p1 = acc1[r] + upd[(size_t)(row0 + 32 + crow) * H + n];
    acc0[r] = p0; acc1[r] = p1;
    ps[crow][n] = p0;
    ps[32 + crow][n] = p1;
  }
  __syncthreads();
  // ---- LN stats: 4 threads per row ----
  {
    int r = tid >> 2, sub = tid & 3;
    float s = 0.f, sq = 0.f;
#pragma unroll
    for (int j = 0; j < 8; ++j) {
      float4 x = *(const float4*)&ps[r][sub * 32 + j * 4];
      s += x.x + x.y + x.z + x.w;
      sq += x.x * x.x + x.y * x.y + x.z * x.z + x.w * x.w;
    }
    s += __shfl_down(s, 2, 4);  s += __shfl_down(s, 1, 4);
    sq += __shfl_down(sq, 2, 4); sq += __shfl_down(sq, 1, 4);
    if (sub == 0) {
      float mu = s * (1.f / 128.f);
      float var = sq * (1.f / 128.f) - mu * mu;
      mus[r] = mu;
      rsd[r] = rsqrtf(var + 1e-5f);
    }
  }
  __syncthreads();
  // ---- normalize, scale by cmask, write ----
  {
    float gn = g[n], bn = beta[n];
#pragma unroll
    for (int r = 0; r < 16; ++r) {
      int crow = (r & 3) + 8 * (r >> 2) + 4 * kh;
      float o0 = ((acc0[r] - mus[crow]) * rsd[crow] * gn + bn) * cmask[row0 + crow];
      float o1 = ((acc1[r] - mus[32 + crow]) * rsd[32 + crow] * gn + bn) * cmask[row0 + 32 + crow];
      upd[(size_t)(row0 + crow) * H + n] = o0;
      upd[(size_t)(row0 + 32 + crow) * H + n] = o1;
    }
  }
}

// ---------------------------------------------- ecacc += sum_l (weighted feed2)
__global__ __launch_bounds__(512) void k_ecadd(const float* __restrict__ wf,
                                               float* __restrict__ ecacc) {
  int b = blockIdx.x, tid = threadIdx.x;
  __shared__ float part[4][128];
  int h = tid & 127, seg = tid >> 7;
  float s = 0.f;
  for (int l = seg; l < L; l += 4) s += wf[(size_t)(b * L + l) * H + h];
  part[seg][h] = s;
  __syncthreads();
  if (tid < 128)
    ecacc[b * H + h] += part[0][h] + part[1][h] + part[2][h] + part[3][h];
}

// ------------ emb fp32 -> frag-linear bf16 hi/lo (padded to NT 32-row tiles)
__global__ __launch_bounds__(256) void k_embconv(const float* __restrict__ emb,
                                                 s16x8* __restrict__ ebh,
                                                 s16x8* __restrict__ ebl) {
  int nt = blockIdx.x;
  int t = threadIdx.x;
  int r = t >> 3, c2 = t & 7;
  int n = nt * 32 + r;
  float vv[16];
  if (n < V) {
    const float4* ep = (const float4*)&emb[(size_t)n * H + c2 * 16];
#pragma unroll
    for (int i = 0; i < 4; ++i) {
      float4 x = ep[i];
      vv[i * 4 + 0] = x.x; vv[i * 4 + 1] = x.y; vv[i * 4 + 2] = x.z; vv[i * 4 + 3] = x.w;
    }
  } else {
#pragma unroll
    for (int i = 0; i < 16; ++i) vv[i] = 0.f;
  }
  s16x8 h0, h1, l0, l1;
#pragma unroll
  for (int i = 0; i < 8; ++i) {
    unsigned short hi = f2bf(vv[i]);
    h0[i] = (short)hi;
    l0[i] = (short)f2bf(vv[i] - __uint_as_float((unsigned)hi << 16));
    unsigned short hj = f2bf(vv[8 + i]);
    h1[i] = (short)hj;
    l1[i] = (short)f2bf(vv[8 + i] - __uint_as_float((unsigned)hj << 16));
  }
  size_t fi0 = ((size_t)nt * 8 + c2) * 64 + r;
  size_t fi1 = fi0 + 32;
  ebh[fi0] = h0; ebh[fi1] = h1;
  ebl[fi0] = l0; ebl[fi1] = l1;
}

// -------------------------------------------------------- gate -> sess, extras
__global__ __launch_bounds__(128) void k_gate(const float* __restrict__ ecacc,
                                              const float* __restrict__ e_s,
                                              const float* __restrict__ gw,
                                              float* __restrict__ sess,
                                              float* __restrict__ out) {
  __shared__ float cat[256];
  int b = blockIdx.x, h = threadIdx.x;
  float ec = ecacc[b * H + h] * (1.f / 3.f);
  float es = e_s[b * H + h];
  cat[h] = ec; cat[128 + h] = es;
  __syncthreads();
  float a = 0.f;
  for (int j = 0; j < 256; ++j) a = fmaf(cat[j], gw[(size_t)j * H + h], a);
  a = 1.f / (1.f + __expf(-a));
  sess[b * H + h] = a * ec + (1.f - a) * es;
  if (b == 0 && h == 0) out[(size_t)B * V] = 0.f;   // con_loss
}

// ---------- scores = sess @ emb^T via bf16x3 MFMA (frag-linear emb) ----------
__global__ __launch_bounds__(256) void k_scores(const float* __restrict__ sess,
                                                const s16x8* __restrict__ ebh,
                                                const s16x8* __restrict__ ebl,
                                                float* __restrict__ out) {
  int wid = threadIdx.x >> 6, lane = threadIdx.x & 63;
  int lr = lane & 31, kh = lane >> 5;
  int mt = blockIdx.y;
  int m = mt * 32 + lr;
  // A fragments from sess (fp32 -> bf16 hi/lo in registers; sess is L2-hot)
  bf16x8 ah[8], al[8];
#pragma unroll
  for (int ks = 0; ks < 8; ++ks) {
    const float* sp = &sess[(size_t)m * H + ks * 16 + kh * 8];
    float4 a = *(const float4*)sp;
    float4 c = *(const float4*)(sp + 4);
    float av[8] = {a.x, a.y, a.z, a.w, c.x, c.y, c.z, c.w};
#pragma unroll
    for (int i = 0; i < 8; ++i) {
      unsigned short hi = f2bf(av[i]);
      ah[ks][i] = (short)hi;
      al[ks][i] = (short)f2bf(av[i] - __uint_as_float((unsigned)hi << 16));
    }
  }
  int ntEnd = min(blockIdx.x * 16 + 16, NT);
  for (int nt = blockIdx.x * 16 + wid; nt < ntEnd; nt += 4) {
    size_t bbase = ((size_t)nt * 8) * 64 + lane;
    f32x16 acc = {};
#pragma unroll
    for (int ks = 0; ks < 8; ++ks) {
      bf16x8 bh = (bf16x8)ebh[bbase + ks * 64];
      bf16x8 bl = (bf16x8)ebl[bbase + ks * 64];
      acc = __builtin_amdgcn_mfma_f32_32x32x16_bf16(ah[ks], bh, acc, 0, 0, 0);
      acc = __builtin_amdgcn_mfma_f32_32x32x16_bf16(al[ks], bh, acc, 0, 0, 0);
      acc = __builtin_amdgcn_mfma_f32_32x32x16_bf16(ah[ks], bl, acc, 0, 0, 0);
    }
    int n = nt * 32 + lr;
    if (n < V) {
#pragma unroll
      for (int r = 0; r < 16; ++r) {
        int row = mt * 32 + (r & 3) + 8 * (r >> 2) + 4 * kh;
        out[(size_t)row * V + n] = acc[r];
      }
    }
  }
}

extern "C" void kernel_launch(void* const* d_in, const int* in_sizes, int n_in,
                              void* d_out, int out_size, void* d_ws, size_t ws_size,
                              hipStream_t stream) {
  const int*   seq  = (const int*)d_in[0];
  const int*   lens = (const int*)d_in[1];
  const int*   rev  = (const int*)d_in[2];
  const float* emb  = (const float*)d_in[3];
  const float* wnz  = (const float*)d_in[4];
  const float* clw  = (const float*)d_in[5];
  const float* w1   = (const float*)d_in[6];
  const float* fb1  = (const float*)d_in[7];
  const float* w2   = (const float*)d_in[8];
  const float* fb2  = (const float*)d_in[9];
  const float* lng  = (const float*)d_in[10];
  const float* lnb  = (const float*)d_in[11];
  const float* gw   = (const float*)d_in[12];
  const float* coff = (const float*)d_in[13];
  float* out = (float*)d_out;

  char* ws = (char*)d_ws;
  size_t off = 0;
  auto alloc = [&](size_t bytes) {
    void* p = ws + off;
    off += (bytes + 255) & ~(size_t)255;
    return p;
  };
  float* hidden = (float*)alloc((size_t)B * L * H * 4);
  float* nrm    = (float*)alloc((size_t)B * L * 4);
  float* S0     = (float*)alloc((size_t)B * L * L * 4);
  float* WS     = (float*)alloc((size_t)B * L * L * 4);
  float* P      = (float*)alloc((size_t)B * L * L * 4);
  float* upd    = (float*)alloc((size_t)B * L * H * 4);
  float* cmask  = (float*)alloc((size_t)B * L * 4);
  int*   cnt    = (int*)alloc((size_t)B * L * 4);
  float* e_s    = (float*)alloc((size_t)B * H * 4);
  float* ecacc  = (float*)alloc((size_t)B * H * 4);
  float* sess   = (float*)alloc((size_t)B * H * 4);
  unsigned char* ET = (unsigned char*)alloc((size_t)B * L * L);
  s16x8* hbh = (s16x8*)alloc((size_t)B * 7 * 8 * 64 * 16);   // frag-linear
  s16x8* wnh = (s16x8*)alloc((size_t)B * 7 * 8 * 64 * 16);
  // lo-residual staging aliases P/upd (first written only inside the layer loop,
  // strictly after k_simws has consumed the staging buffers)
  s16x8* hbl = (s16x8*)P;
  s16x8* wnl = (s16x8*)upd;
  // emb bf16 hi/lo staging aliases S0/WS (dead after the last k_rowpass);
  // NT*8*64*16 B = 12.8 MB each <= 41 MB each
  s16x8* ebh = (s16x8*)S0;
  s16x8* ebl = (s16x8*)WS;

  k_embed<<<B * 7, 256, 0, stream>>>(seq, rev, emb, wnz, hidden, nrm,
                                     hbh, hbl, wnh, wnl);
  k_init<<<B, 512, 0, stream>>>(lens, hidden, ecacc, e_s);
  k_simws<<<B * 14, 256, 0, stream>>>(hbh, hbl, wnh, wnl, nrm, rev, clw, S0, WS);

  for (int i = 0; i < 2; ++i) {
    hipMemsetAsync(ET, 0, (size_t)B * L * L, stream);
    k_rowpass<<<B * 7, 256, 0, stream>>>(S0, WS, coff + (size_t)i * B * L * L,
                                         lens, P, ET);
    k_gather<<<B * L / 4, 512, 0, stream>>>(P, ET, hidden, cmask, upd);
    k_cnorm<<<B, 64, 0, stream>>>(cmask);
    k_ffn<<<B * L / 64, 256, 0, stream>>>(upd, w1, fb1, w2, fb2, lng, lnb, cmask);
    k_ecadd<<<B, 512, 0, stream>>>(upd, ecacc);
  }

  k_embconv<<<NT, 256, 0, stream>>>(emb, ebh, ebl);
  k_gate<<<B, 128, 0, stream>>>(ecacc, e_s, gw, sess, out);
  k_scores<<<dim3((NT + 15) / 16, 8), 256, 0, stream>>>(sess, ebh, ebl, out);
}

// Round 14
// 443.959 us; speedup vs baseline: 1.0438x; 1.0438x over previous
//
#include <hip/hip_runtime.h>
#include <cstdint>
#include <cstddef>

namespace {
constexpr int B = 256, L = 200, H = 128, V = 50000, TK = 20;
constexpr int NT = 1563;                   // ceil(V/32)
constexpr float NEGV = -1e10f;
}

using bf16x8 = __attribute__((ext_vector_type(8))) short;
using s16x8  = __attribute__((ext_vector_type(8))) short;
using f32x16 = __attribute__((ext_vector_type(16))) float;

__device__ inline unsigned short f2bf(float f) {
  unsigned int u = __float_as_uint(f);
  unsigned int r = (u + 0x7fffu + ((u >> 16) & 1u)) >> 16;   // RNE
  return (unsigned short)r;
}

// ---- 16-lane-group DPP reductions ------------------------------------------
#define DPP_QUAD_XOR1 0xB1
#define DPP_QUAD_XOR2 0x4E
#define DPP_ROW_HMIRR 0x141
#define DPP_ROW_MIRR  0x140

template <int CTRL>
__device__ inline unsigned dpp16_max_step(unsigned v) {
  unsigned t = (unsigned)__builtin_amdgcn_update_dpp(0, (int)v, CTRL, 0xF, 0xF, true);
  return v > t ? v : t;
}
__device__ inline unsigned grp16_max(unsigned v) {
  v = dpp16_max_step<DPP_QUAD_XOR1>(v);
  v = dpp16_max_step<DPP_QUAD_XOR2>(v);
  v = dpp16_max_step<DPP_ROW_HMIRR>(v);
  v = dpp16_max_step<DPP_ROW_MIRR>(v);
  return v;                                   // uniform within each 16-group
}
template <int CTRL>
__device__ inline float dpp16_add_step(float v) {
  int t = __builtin_amdgcn_update_dpp(0, __float_as_int(v), CTRL, 0xF, 0xF, true);
  return v + __int_as_float(t);
}
__device__ inline float grp16_sum(float v) {
  v = dpp16_add_step<DPP_QUAD_XOR1>(v);
  v = dpp16_add_step<DPP_QUAD_XOR2>(v);
  v = dpp16_add_step<DPP_ROW_HMIRR>(v);
  v = dpp16_add_step<DPP_ROW_MIRR>(v);
  return v;
}

__device__ inline unsigned f2key(float f) {        // order-preserving, bijective
  unsigned b = __float_as_uint(f);
  unsigned m = (unsigned)((int)b >> 31);
  return b ^ (m | 0x80000000u);
}
__device__ inline float key2f(unsigned u) {
  unsigned b = (u & 0x80000000u) ? (u & 0x7fffffffu) : ~u;
  return __uint_as_float(b);
}

// ---- embed + norm + frag-linear bf16 hi/lo staging --------------------------
__global__ __launch_bounds__(256) void k_embed(const int* __restrict__ seq,
                                               const int* __restrict__ rev,
                                               const float* __restrict__ emb,
                                               const float* __restrict__ wnoise,
                                               float* __restrict__ hidden,
                                               float* __restrict__ nrm,
                                               s16x8* __restrict__ hbh,
                                               s16x8* __restrict__ hbl,
                                               s16x8* __restrict__ wnh,
                                               s16x8* __restrict__ wnl) {
  int b = blockIdx.x / 7, lt = blockIdx.x % 7;
  int t = threadIdx.x;
  int r = t >> 3, c2 = t & 7;                 // row-in-tile, 16-elem h-chunk
  int l = lt * 32 + r;
  bool valid = l < L;
  float vv[16], wv[16];
  if (valid) {
    int row = b * L + l;
    int tok = seq[row];
    const float4* ep = (const float4*)&emb[(size_t)tok * H + c2 * 16];
    const float4* wp = (const float4*)&wnoise[(size_t)rev[row] * H + c2 * 16];
#pragma unroll
    for (int i = 0; i < 4; ++i) {
      float4 x = ep[i];
      vv[i * 4 + 0] = x.x; vv[i * 4 + 1] = x.y; vv[i * 4 + 2] = x.z; vv[i * 4 + 3] = x.w;
      float4 y = wp[i];
      wv[i * 4 + 0] = y.x; wv[i * 4 + 1] = y.y; wv[i * 4 + 2] = y.z; wv[i * 4 + 3] = y.w;
    }
  } else {
#pragma unroll
    for (int i = 0; i < 16; ++i) { vv[i] = 0.f; wv[i] = 0.f; }
  }
  if (valid) {
    int row = b * L + l;
#pragma unroll
    for (int i = 0; i < 4; ++i)
      *(float4*)&hidden[(size_t)row * H + c2 * 16 + i * 4] =
          make_float4(vv[i * 4], vv[i * 4 + 1], vv[i * 4 + 2], vv[i * 4 + 3]);
    float s = 0.f;
#pragma unroll
    for (int i = 0; i < 16; ++i) s += vv[i] * vv[i];
    s += __shfl_down(s, 4, 8);
    s += __shfl_down(s, 2, 8);
    s += __shfl_down(s, 1, 8);
    if (c2 == 0) nrm[row] = sqrtf(s);
  }
  s16x8 h0, h1, l0, l1, w0, w1, x0, x1;
#pragma unroll
  for (int i = 0; i < 8; ++i) {
    unsigned short hi = f2bf(vv[i]);
    h0[i] = (short)hi;
    l0[i] = (short)f2bf(vv[i] - __uint_as_float((unsigned)hi << 16));
    unsigned short wh = f2bf(wv[i]);
    w0[i] = (short)wh;
    x0[i] = (short)f2bf(wv[i] - __uint_as_float((unsigned)wh << 16));
  }
#pragma unroll
  for (int i = 0; i < 8; ++i) {
    unsigned short hi = f2bf(vv[8 + i]);
    h1[i] = (short)hi;
    l1[i] = (short)f2bf(vv[8 + i] - __uint_as_float((unsigned)hi << 16));
    unsigned short wh = f2bf(wv[8 + i]);
    w1[i] = (short)wh;
    x1[i] = (short)f2bf(wv[8 + i] - __uint_as_float((unsigned)wh << 16));
  }
  size_t fi0 = ((size_t)(b * 7 + lt) * 8 + c2) * 64 + r;   // kh=0
  size_t fi1 = fi0 + 32;                                   // kh=1
  hbh[fi0] = h0; hbh[fi1] = h1;
  hbl[fi0] = l0; hbl[fi1] = l1;
  wnh[fi0] = w0; wnh[fi1] = w1;
  wnl[fi0] = x0; wnl[fi1] = x1;
}

// ------------------------------------------ slen, zero_layer (into ecacc), e_s
__global__ __launch_bounds__(512) void k_init(const int* __restrict__ lengths,
                                              const float* __restrict__ hidden,
                                              float* __restrict__ ecacc,
                                              float* __restrict__ e_s) {
  int b = blockIdx.x, tid = threadIdx.x;
  __shared__ float part[4][128];
  __shared__ int wcnt[8];
  __shared__ int s_slen;
  int c = (tid < L && lengths[b * L + tid] > 0) ? 1 : 0;
  for (int o = 32; o > 0; o >>= 1) c += __shfl_down(c, o, 64);
  if ((tid & 63) == 0) wcnt[tid >> 6] = c;
  __syncthreads();
  if (tid == 0) {
    int s = 0;
#pragma unroll
    for (int i = 0; i < 8; ++i) s += wcnt[i];
    s_slen = s;
  }
  int h = tid & 127, seg = tid >> 7;
  float s = 0.f;
  for (int l = seg; l < L; l += 4) s += hidden[(size_t)(b * L + l) * H + h];
  part[seg][h] = s;
  __syncthreads();
  if (tid < 128) {
    float tot = part[0][h] + part[1][h] + part[2][h] + part[3][h];
    int slen = s_slen;
    ecacc[b * H + h] = tot / (float)slen;
    e_s[b * H + h] = hidden[(size_t)(b * L + slen - 1) * H + h];
  }
}

// ---- S0 = cosine sim (+diag), WS = softplus(hidden·wn), bf16x3 split MFMA ---
// one 32x32 mtile per wave; grid = 8 XCD * 32 b * 7 lt * 2 half
__global__ __launch_bounds__(256) void k_simws(const s16x8* __restrict__ hbh,
                                               const s16x8* __restrict__ hbl,
                                               const s16x8* __restrict__ wnh,
                                               const s16x8* __restrict__ wnl,
                                               const float* __restrict__ nrm,
                                               const int* __restrict__ rev,
                                               const float* __restrict__ cluster,
                                               float* __restrict__ S0,
                                               float* __restrict__ WS) {
  int orig = blockIdx.x;                     // 0..3583
  int xcd = orig & 7, slot = orig >> 3;      // slot 0..447
  int b = xcd * 32 + slot / 14;
  int rem = slot % 14;
  int lt = rem >> 1, half = rem & 1;
  int wid = threadIdx.x >> 6, lane = threadIdx.x & 63;
  int mt = half * 4 + wid;                   // 0..7
  if (mt > 6) return;                        // one idle wave in odd halves
  int lr = lane & 31, kh = lane >> 5;
  size_t abase = ((size_t)(b * 7 + lt) * 8) * 64 + lane;
  bf16x8 ah[8], al[8];
#pragma unroll
  for (int ks = 0; ks < 8; ++ks) {
    ah[ks] = (bf16x8)hbh[abase + ks * 64];
    al[ks] = (bf16x8)hbl[abase + ks * 64];
  }
  size_t bbase = ((size_t)(b * 7 + mt) * 8) * 64 + lane;
  f32x16 accs = {}, accw = {};
#pragma unroll
  for (int ks = 0; ks < 8; ++ks) {
    bf16x8 bhh = (bf16x8)hbh[bbase + ks * 64];
    bf16x8 bhl = (bf16x8)hbl[bbase + ks * 64];
    bf16x8 bwh = (bf16x8)wnh[bbase + ks * 64];
    bf16x8 bwl = (bf16x8)wnl[bbase + ks * 64];
    accs = __builtin_amdgcn_mfma_f32_32x32x16_bf16(ah[ks], bhh, accs, 0, 0, 0);
    accs = __builtin_amdgcn_mfma_f32_32x32x16_bf16(ah[ks], bhl, accs, 0, 0, 0);
    accs = __builtin_amdgcn_mfma_f32_32x32x16_bf16(al[ks], bhh, accs, 0, 0, 0);
    accw = __builtin_amdgcn_mfma_f32_32x32x16_bf16(ah[ks], bwh, accw, 0, 0, 0);
    accw = __builtin_amdgcn_mfma_f32_32x32x16_bf16(ah[ks], bwl, accw, 0, 0, 0);
    accw = __builtin_amdgcn_mfma_f32_32x32x16_bf16(al[ks], bwh, accw, 0, 0, 0);
  }
  int m = mt * 32 + lr;
  if (m < L) {
    float nm = nrm[b * L + m];
#pragma unroll
    for (int r = 0; r < 16; ++r) {
      int row = lt * 32 + (r & 3) + 8 * (r >> 2) + 4 * kh;
      if (row < L) {
        float nl = nrm[b * L + row];
        float s0 = accs[r] * __builtin_amdgcn_rcpf(nl * nm + 1e-6f);
        if (row == m) s0 += cluster[rev[b * L + row]];
        size_t o = (size_t)(b * L + row) * L + m;
        S0[o] = s0;
        float x = accw[r];
        WS[o] = (x > 1.f) ? x : __logf(1.f + __expf(x));
      }
    }
  }
}

// ------- per row: msim in regs, candidate-cached top-K (LDS key mirror),
// softmax. 4 waves/block, 4 rows/wave (one per 16-lane group). [R11 version]
__global__ __launch_bounds__(256) void k_rowpass(const float* __restrict__ S0,
                                                 const float* __restrict__ WS,
                                                 const float* __restrict__ coff_i,
                                                 const int* __restrict__ lengths,
                                                 float* __restrict__ P,
                                                 unsigned char* __restrict__ ET) {
  __shared__ unsigned klds[256 * 13];        // per-thread key mirror (self-access)
  int wid = threadIdx.x >> 6, lane = threadIdx.x & 63;
  int g = lane >> 4, q = lane & 15;
  int bb = blockIdx.x / 13, blk = blockIdx.x % 13;
  int l = blk * 16 + wid * 4 + g;
  bool lvalid = l < L;
  int lrow = bb * L + (lvalid ? l : 0);
  bool mask_l = lvalid && (lengths[lrow] > 0);
  size_t base = (size_t)lrow * L;
  int kbase = threadIdx.x * 13;
  float val[13]; unsigned vmask = 0;
  unsigned h0 = 0, h1 = 0, h2 = 0; int j0 = 0, j1 = 0, j2 = 0;
#pragma unroll
  for (int j = 0; j < 13; ++j) {
    int m = q + 16 * j;
    float v = 0.f; bool ok = false;
    if (mask_l && m < L) {
      ok = lengths[bb * L + m] > 0;
      if (ok) v = S0[base + m] + coff_i[base + m] * WS[base + m];
    }
    val[j] = v;
    unsigned k = ok ? f2key(v) : 0u;
    vmask |= ok ? (1u << j) : 0u;
    klds[kbase + j] = k;
    // per-lane sorted top-3 (strict > keeps lowest j on ties = lowest m)
    if (k > h0)      { h2 = h1; j2 = j1; h1 = h0; j1 = j0; h0 = k; j0 = j; }
    else if (k > h1) { h2 = h1; j2 = j1; h1 = k; j1 = j; }
    else if (k > h2) { h2 = k; j2 = j; }
  }
  unsigned cc = h0; int ccj = j0;            // current candidate
  int consumed = 0;
  unsigned Mu = 0u;
  for (int t = 0; t < TK; ++t) {
    unsigned gm = grp16_max(cc);
    if (t == 0) Mu = gm;
    if (__all(gm == 0u)) break;              // all 4 groups exhausted
    unsigned long long bal = __ballot(cc == gm && gm != 0u);
    unsigned long long mine = bal & (0xFFFFull << (g * 16));
    int owner = mine ? (int)__builtin_ctzll(mine) : -1;
    if (lane == owner) {                     // lowest lane of group (tie ok)
      int m = q + 16 * ccj;
      ET[((size_t)bb * L + m) * L + l] = 1;
      klds[kbase + ccj] = 0u;
      ++consumed;
      if (consumed == 1)      { cc = h1; ccj = j1; }
      else if (consumed == 2) { cc = h2; ccj = j2; }
      else {                                 // rare exact rescan (own LDS keys)
        unsigned c2 = 0; int cj2 = 0;
#pragma unroll
        for (int j = 0; j < 13; ++j) {
          unsigned k2 = klds[kbase + j];
          if (k2 > c2) { c2 = k2; cj2 = j; }
        }
        cc = c2; ccj = cj2;
      }
    }
  }
  // softmax over the row (invalid entries contribute exactly 0)
  float M = key2f(Mu);
  float e[13]; float s = 0.f;
#pragma unroll
  for (int j = 0; j < 13; ++j) {
    float ev = ((vmask >> j) & 1u) ? __expf(val[j] - M) : 0.f;
    e[j] = ev; s += ev;
  }
  s = grp16_sum(s);
  float inv = (s > 0.f) ? __builtin_amdgcn_rcpf(s) : 0.f;
  if (lvalid) {
#pragma unroll
    for (int j = 0; j < 13; ++j) {
      int m = q + 16 * j;
      if (m < L) P[base + m] = e[j] * inv;
    }
  }
}

// ---- FUSED compact+update: ssm row -> cmask + LDS edge list -> gather -------
// 512 threads, 4 rows/block: waves 0-3 compact row 4*bid+wv (waves 4-7 wait);
// then all 512 threads gather (128 thr/row).
__global__ __launch_bounds__(512) void k_gather(const float* __restrict__ P,
                                                const unsigned char* __restrict__ ET,
                                                const float* __restrict__ hidden,
                                                float* __restrict__ cmask,
                                                float* __restrict__ upd) {
  __shared__ float wls[4][224];
  __shared__ unsigned char ils[4][224];
  __shared__ int s_cnt[4];
  int wv = threadIdx.x >> 6, lane = threadIdx.x & 63;
  if (wv < 4) {                              // only 4 compaction waves
    int rowW = blockIdx.x * 4 + wv;
    size_t baseW = (size_t)rowW * L;
    float w[4]; float s = 0.f;
#pragma unroll
    for (int j = 0; j < 4; ++j) {
      int m = lane + 64 * j;
      float ww = 0.f;
      if (m < L) ww = P[baseW + m] * (float)ET[baseW + m];
      w[j] = ww; s += ww;
    }
    float ssum = s;
    for (int off = 1; off < 64; off <<= 1) ssum += __shfl_xor(ssum, off, 64);
    if (lane == 0) cmask[rowW] = ssum;
    int pos_base = 0;
#pragma unroll
    for (int j = 0; j < 4; ++j) {
      bool nz = (w[j] != 0.f);
      unsigned long long mk = __ballot(nz);
      int rank = __popcll(mk & ((1ull << lane) - 1ull));
      if (nz) {
        int pos = pos_base + rank;
        ils[wv][pos] = (unsigned char)(lane + 64 * j);
        wls[wv][pos] = w[j];
      }
      pos_base += (int)__popcll(mk);
    }
    if (lane == 0) s_cnt[wv] = pos_base;
    int padEnd = ((pos_base + TK - 1) / TK) * TK;   // zero-pad to 20-multiple
    for (int p = pos_base + lane; p < padEnd; p += 64) {
      ils[wv][p] = 0; wls[wv][p] = 0.f;
    }
  }
  __syncthreads();
  int half = threadIdx.x >> 7;               // 0..3 -> row in block
  int h = threadIdx.x & 127;
  int row = blockIdx.x * 4 + half;
  int b = row / L;
  int n = s_cnt[half];
  float acc = 0.f;
  for (int e0 = 0; e0 < n; e0 += TK) {
    float w[TK]; int m[TK];
#pragma unroll
    for (int e = 0; e < TK; ++e) { w[e] = wls[half][e0 + e]; m[e] = ils[half][e0 + e]; }
    float hv[TK];
#pragma unroll
    for (int e = 0; e < TK; ++e)
      hv[e] = hidden[(size_t)(b * L + m[e]) * H + h];
#pragma unroll
    for (int e = 0; e < TK; ++e)
      acc += w[e] * hv[e];                   // padded entries are exact zeros
  }
  upd[(size_t)row * H + h] = acc;
}

// -------------------------------------------- cmask /= max(||cmask||_2, 1e-12)
__global__ __launch_bounds__(64) void k_cnorm(float* __restrict__ cmask) {
  int b = blockIdx.x, lane = threadIdx.x;   // 64 threads
  float v[4]; float s = 0.f;
#pragma unroll
  for (int j = 0; j < 4; ++j) {
    int l = lane + 64 * j;
    float x = (l < L) ? cmask[b * L + l] : 0.f;
    v[j] = x; s += x * x;
  }
  for (int off = 1; off < 64; off <<= 1) s += __shfl_xor(s, off, 64);
  float inv = 1.f / fmaxf(sqrtf(s), 1e-12f);
#pragma unroll
  for (int j = 0; j < 4; ++j) {
    int l = lane + 64 * j;
    if (l < L) cmask[b * L + l] = v[j] * inv;
  }
}

// ----- FFN + residual + LN via bf16x3 MFMA, weighted by cmask, in-place ------
__global__ __launch_bounds__(256) void k_ffn(float* __restrict__ upd,
                                             const float* __restrict__ W1,
                                             const float* __restrict__ b1,
                                             const float* __restrict__ W2,
                                             const float* __restrict__ b2,
                                             const float* __restrict__ g,
                                             const float* __restrict__ beta,
                                             const float* __restrict__ cmask) {
  constexpr int AS = 136;                            // short stride (16B-aligned rows)
  __shared__ __align__(16) char smem[4 * 64 * AS * 2];  // 69632 B
  short* ahs = (short*)smem;                         // A hi  [64][AS]
  short* als = ahs + 64 * AS;                        // A lo
  short* f1h = (short*)(smem + 2 * 64 * AS * 2);     // feed1 hi
  short* f1l = f1h + 64 * AS;
  float (*ps)[132] = (float (*)[132])smem;           // aliases A (dead after GEMM1)
  __shared__ float mus[64], rsd[64];
  int row0 = blockIdx.x * 64;
  int tid = threadIdx.x;
  int wid = tid >> 6, lane = tid & 63;
  int lr = lane & 31, kh = lane >> 5;
  int n0 = wid * 32;
  int n = n0 + lr;
  // ---- stage upd -> bf16 hi/lo LDS ----
#pragma unroll
  for (int it = 0; it < 8; ++it) {
    int f = it * 256 + tid;
    int r = f >> 5, c4 = (f & 31) * 4;
    float4 v = *(const float4*)&upd[(size_t)(row0 + r) * H + c4];
    float vv[4] = {v.x, v.y, v.z, v.w};
    unsigned short hh[4]; short ll[4];
#pragma unroll
    for (int q2 = 0; q2 < 4; ++q2) {
      hh[q2] = f2bf(vv[q2]);
      ll[q2] = (short)f2bf(vv[q2] - __uint_as_float((unsigned)hh[q2] << 16));
    }
    uint2 ph = make_uint2((unsigned)hh[0] | ((unsigned)hh[1] << 16),
                          (unsigned)hh[2] | ((unsigned)hh[3] << 16));
    uint2 pl = make_uint2((unsigned short)ll[0] | ((unsigned)(unsigned short)ll[1] << 16),
                          (unsigned short)ll[2] | ((unsigned)(unsigned short)ll[3] << 16));
    *(uint2*)&ahs[r * AS + c4] = ph;
    *(uint2*)&als[r * AS + c4] = pl;
  }
  __syncthreads();
  // ---- W1 fragments ----
  bf16x8 wfh[8], wfl[8];
#pragma unroll
  for (int ks = 0; ks < 8; ++ks) {
#pragma unroll
    for (int i = 0; i < 8; ++i) {
      float w = W1[(size_t)(ks * 16 + kh * 8 + i) * H + n];
      unsigned short hi = f2bf(w);
      wfh[ks][i] = (short)hi;
      wfl[ks][i] = (short)f2bf(w - __uint_as_float((unsigned)hi << 16));
    }
  }
  // ---- GEMM1: feed1 = relu(upd @ W1 + b1) ----
  f32x16 acc0, acc1;
  {
    float bv = b1[n];
#pragma unroll
    for (int r = 0; r < 16; ++r) { acc0[r] = bv; acc1[r] = bv; }
  }
#pragma unroll
  for (int ks = 0; ks < 8; ++ks) {
    bf16x8 xh0 = *(const bf16x8*)&ahs[(0 * 32 + lr) * AS + ks * 16 + kh * 8];
    bf16x8 xl0 = *(const bf16x8*)&als[(0 * 32 + lr) * AS + ks * 16 + kh * 8];
    bf16x8 xh1 = *(const bf16x8*)&ahs[(1 * 32 + lr) * AS + ks * 16 + kh * 8];
    bf16x8 xl1 = *(const bf16x8*)&als[(1 * 32 + lr) * AS + ks * 16 + kh * 8];
    acc0 = __builtin_amdgcn_mfma_f32_32x32x16_bf16(xh0, wfh[ks], acc0, 0, 0, 0);
    acc0 = __builtin_amdgcn_mfma_f32_32x32x16_bf16(xl0, wfh[ks], acc0, 0, 0, 0);
    acc0 = __builtin_amdgcn_mfma_f32_32x32x16_bf16(xh0, wfl[ks], acc0, 0, 0, 0);
    acc1 = __builtin_amdgcn_mfma_f32_32x32x16_bf16(xh1, wfh[ks], acc1, 0, 0, 0);
    acc1 = __builtin_amdgcn_mfma_f32_32x32x16_bf16(xl1, wfh[ks], acc1, 0, 0, 0);
    acc1 = __builtin_amdgcn_mfma_f32_32x32x16_bf16(xh1, wfl[ks], acc1, 0, 0, 0);
  }
  // relu -> f1 hi/lo LDS (C layout: row=(r&3)+8*(r>>2)+4*kh, col=n)
#pragma unroll
  for (int r = 0; r < 16; ++r) {
    int crow = (r & 3) + 8 * (r >> 2) + 4 * kh;
    float f0 = fmaxf(acc0[r], 0.f);
    unsigned short h0 = f2bf(f0);
    f1h[crow * AS + n] = (short)h0;
    f1l[crow * AS + n] = (short)f2bf(f0 - __uint_as_float((unsigned)h0 << 16));
    float f1v = fmaxf(acc1[r], 0.f);
    unsigned short h1 = f2bf(f1v);
    f1h[(32 + crow) * AS + n] = (short)h1;
    f1l[(32 + crow) * AS + n] = (short)f2bf(f1v - __uint_as_float((unsigned)h1 << 16));
  }
  __syncthreads();                                    // f1 complete; A region dead
  // ---- W2 fragments ----
#pragma unroll
  for (int ks = 0; ks < 8; ++ks) {
#pragma unroll
    for (int i = 0; i < 8; ++i) {
      float w = W2[(size_t)(ks * 16 + kh * 8 + i) * H + n];
      unsigned short hi = f2bf(w);
      wfh[ks][i] = (short)hi;
      wfl[ks][i] = (short)f2bf(w - __uint_as_float((unsigned)hi << 16));
    }
  }
  // ---- GEMM2: pre = feed1 @ W2 + b2 + upd ----
  {
    float bv = b2[n];
#pragma unroll
    for (int r = 0; r < 16; ++r) { acc0[r] = bv; acc1[r] = bv; }
  }
#pragma unroll
  for (int ks = 0; ks < 8; ++ks) {
    bf16x8 xh0 = *(const bf16x8*)&f1h[(0 * 32 + lr) * AS + ks * 16 + kh * 8];
    bf16x8 xl0 = *(const bf16x8*)&f1l[(0 * 32 + lr) * AS + ks * 16 + kh * 8];
    bf16x8 xh1 = *(const bf16x8*)&f1h[(1 * 32 + lr) * AS + ks * 16 + kh * 8];
    bf16x8 xl1 = *(const bf16x8*)&f1l[(1 * 32 + lr) * AS + ks * 16 + kh * 8];
    acc0 = __builtin_amdgcn_mfma_f32_32x32x16_bf16(xh0, wfh[ks], acc0, 0, 0, 0);
    acc0 = __builtin_amdgcn_mfma_f32_32x32x16_bf16(xl0, wfh[ks], acc0, 0, 0, 0);
    acc0 = __builtin_amdgcn_mfma_f32_32x32x16_bf16(xh0, wfl[ks], acc0, 0, 0, 0);
    acc1 = __builtin_amdgcn_mfma_f32_32x32x16_bf16(xh1, wfh[ks], acc1, 0, 0, 0);
    acc1 = __builtin_amdgcn_mfma_f32_32x32x16_bf16(xl1, wfh[ks], acc1, 0, 0, 0);
    acc1 = __builtin_amdgcn_mfma_f32_32x32x16_bf16(xh1, wfl[ks], acc1, 0, 0, 0);
  }
  // residual + write ps (pre) — ps aliases A region (dead since barrier)
#pragma unroll
  for (int r = 0; r < 16; ++r) {
    int crow = (r & 3) + 8 * (r >> 2) + 4 * kh;
    float p0 = acc0[r] + upd[(size_t)(row0 + crow) * H + n];
    float p1 = acc1[r] + upd[(size_t)(row0 + 32 + crow) * H + n];
    acc0[r] = p0; acc1[r] = p1;
    ps[crow][n] = p0;
    ps[32 + crow][n] = p1;
  }
  __syncthreads();
  // ---- LN stats: 4 threads per row ----
  {
    int r = tid >> 2, sub = tid & 3;
    float s = 0.f, sq = 0.f;
#pragma unroll
    for (int j = 0; j < 8; ++j) {
      float4 x = *(const float4*)&ps[r][sub * 32 + j * 4];
      s += x.x + x.y + x.z + x.w;
      sq += x.x * x.x + x.y * x.y + x.z * x.z + x.w * x.w;
    }
    s += __shfl_down(s, 2, 4);  s += __shfl_down(s, 1, 4);
    sq += __shfl_down(sq, 2, 4); sq += __shfl_down(sq, 1, 4);
    if (sub == 0) {
      float mu = s * (1.f / 128.f);
      float var = sq * (1.f / 128.f) - mu * mu;
      mus[r] = mu;
      rsd[r] = rsqrtf(var + 1e-5f);
    }
  }
  __syncthreads();
  // ---- normalize, scale by cmask, write ----
  {
    float gn = g[n], bn = beta[n];
#pragma unroll
    for (int r = 0; r < 16; ++r) {
      int crow = (r & 3) + 8 * (r >> 2) + 4 * kh;
      float o0 = ((acc0[r] - mus[crow]) * rsd[crow] * gn + bn) * cmask[row0 + crow];
      float o1 = ((acc1[r] - mus[32 + crow]) * rsd[32 + crow] * gn + bn) * cmask[row0 + 32 + crow];
      upd[(size_t)(row0 + crow) * H + n] = o0;
      upd[(size_t)(row0 + 32 + crow) * H + n] = o1;
    }
  }
}

// ---------------------------------------------- ecacc += sum_l (weighted feed2)
__global__ __launch_bounds__(512) void k_ecadd(const float* __restrict__ wf,
                                               float* __restrict__ ecacc) {
  int b = blockIdx.x, tid = threadIdx.x;
  __shared__ float part[4][128];
  int h = tid & 127, seg = tid >> 7;
  float s = 0.f;
  for (int l = seg; l < L; l += 4) s += wf[(size_t)(b * L + l) * H + h];
  part[seg][h] = s;
  __syncthreads();
  if (tid < 128)
    ecacc[b * H + h] += part[0][h] + part[1][h] + part[2][h] + part[3][h];
}

// ------------ emb fp32 -> frag-linear bf16 hi/lo (padded to NT 32-row tiles)
__global__ __launch_bounds__(256) void k_embconv(const float* __restrict__ emb,
                                                 s16x8* __restrict__ ebh,
                                                 s16x8* __restrict__ ebl) {
  int nt = blockIdx.x;
  int t = threadIdx.x;
  int r = t >> 3, c2 = t & 7;
  int n = nt * 32 + r;
  float vv[16];
  if (n < V) {
    const float4* ep = (const float4*)&emb[(size_t)n * H + c2 * 16];
#pragma unroll
    for (int i = 0; i < 4; ++i) {
      float4 x = ep[i];
      vv[i * 4 + 0] = x.x; vv[i * 4 + 1] = x.y; vv[i * 4 + 2] = x.z; vv[i * 4 + 3] = x.w;
    }
  } else {
#pragma unroll
    for (int i = 0; i < 16; ++i) vv[i] = 0.f;
  }
  s16x8 h0, h1, l0, l1;
#pragma unroll
  for (int i = 0; i < 8; ++i) {
    unsigned short hi = f2bf(vv[i]);
    h0[i] = (short)hi;
    l0[i] = (short)f2bf(vv[i] - __uint_as_float((unsigned)hi << 16));
    unsigned short hj = f2bf(vv[8 + i]);
    h1[i] = (short)hj;
    l1[i] = (short)f2bf(vv[8 + i] - __uint_as_float((unsigned)hj << 16));
  }
  size_t fi0 = ((size_t)nt * 8 + c2) * 64 + r;
  size_t fi1 = fi0 + 32;
  ebh[fi0] = h0; ebh[fi1] = h1;
  ebl[fi0] = l0; ebl[fi1] = l1;
}

// -------------------------------------------------------- gate -> sess, extras
__global__ __launch_bounds__(128) void k_gate(const float* __restrict__ ecacc,
                                              const float* __restrict__ e_s,
                                              const float* __restrict__ gw,
                                              float* __restrict__ sess,
                                              float* __restrict__ out) {
  __shared__ float cat[256];
  int b = blockIdx.x, h = threadIdx.x;
  float ec = ecacc[b * H + h] * (1.f / 3.f);
  float es = e_s[b * H + h];
  cat[h] = ec; cat[128 + h] = es;
  __syncthreads();
  float a = 0.f;
  for (int j = 0; j < 256; ++j) a = fmaf(cat[j], gw[(size_t)j * H + h], a);
  a = 1.f / (1.f + __expf(-a));
  sess[b * H + h] = a * ec + (1.f - a) * es;
  if (b == 0 && h == 0) out[(size_t)B * V] = 0.f;   // con_loss
}

// ---------- scores = sess @ emb^T via bf16x3 MFMA (frag-linear emb) ----------
__global__ __launch_bounds__(256) void k_scores(const float* __restrict__ sess,
                                                const s16x8* __restrict__ ebh,
                                                const s16x8* __restrict__ ebl,
                                                float* __restrict__ out) {
  int wid = threadIdx.x >> 6, lane = threadIdx.x & 63;
  int lr = lane & 31, kh = lane >> 5;
  int mt = blockIdx.y;
  int m = mt * 32 + lr;
  // A fragments from sess (fp32 -> bf16 hi/lo in registers; sess is L2-hot)
  bf16x8 ah[8], al[8];
#pragma unroll
  for (int ks = 0; ks < 8; ++ks) {
    const float* sp = &sess[(size_t)m * H + ks * 16 + kh * 8];
    float4 a = *(const float4*)sp;
    float4 c = *(const float4*)(sp + 4);
    float av[8] = {a.x, a.y, a.z, a.w, c.x, c.y, c.z, c.w};
#pragma unroll
    for (int i = 0; i < 8; ++i) {
      unsigned short hi = f2bf(av[i]);
      ah[ks][i] = (short)hi;
      al[ks][i] = (short)f2bf(av[i] - __uint_as_float((unsigned)hi << 16));
    }
  }
  int ntEnd = min(blockIdx.x * 16 + 16, NT);
  for (int nt = blockIdx.x * 16 + wid; nt < ntEnd; nt += 4) {
    size_t bbase = ((size_t)nt * 8) * 64 + lane;
    f32x16 acc = {};
#pragma unroll
    for (int ks = 0; ks < 8; ++ks) {
      bf16x8 bh = (bf16x8)ebh[bbase + ks * 64];
      bf16x8 bl = (bf16x8)ebl[bbase + ks * 64];
      acc = __builtin_amdgcn_mfma_f32_32x32x16_bf16(ah[ks], bh, acc, 0, 0, 0);
      acc = __builtin_amdgcn_mfma_f32_32x32x16_bf16(al[ks], bh, acc, 0, 0, 0);
      acc = __builtin_amdgcn_mfma_f32_32x32x16_bf16(ah[ks], bl, acc, 0, 0, 0);
    }
    int n = nt * 32 + lr;
    if (n < V) {
#pragma unroll
      for (int r = 0; r < 16; ++r) {
        int row = mt * 32 + (r & 3) + 8 * (r >> 2) + 4 * kh;
        out[(size_t)row * V + n] = acc[r];
      }
    }
  }
}

extern "C" void kernel_launch(void* const* d_in, const int* in_sizes, int n_in,
                              void* d_out, int out_size, void* d_ws, size_t ws_size,
                              hipStream_t stream) {
  const int*   seq  = (const int*)d_in[0];
  const int*   lens = (const int*)d_in[1];
  const int*   rev  = (const int*)d_in[2];
  const float* emb  = (const float*)d_in[3];
  const float* wnz  = (const float*)d_in[4];
  const float* clw  = (const float*)d_in[5];
  const float* w1   = (const float*)d_in[6];
  const float* fb1  = (const float*)d_in[7];
  const float* w2   = (const float*)d_in[8];
  const float* fb2  = (const float*)d_in[9];
  const float* lng  = (const float*)d_in[10];
  const float* lnb  = (const float*)d_in[11];
  const float* gw   = (const float*)d_in[12];
  const float* coff = (const float*)d_in[13];
  float* out = (float*)d_out;

  char* ws = (char*)d_ws;
  size_t off = 0;
  auto alloc = [&](size_t bytes) {
    void* p = ws + off;
    off += (bytes + 255) & ~(size_t)255;
    return p;
  };
  float* hidden = (float*)alloc((size_t)B * L * H * 4);
  float* nrm    = (float*)alloc((size_t)B * L * 4);
  float* S0     = (float*)alloc((size_t)B * L * L * 4);
  float* WS     = (float*)alloc((size_t)B * L * L * 4);
  float* P      = (float*)alloc((size_t)B * L * L * 4);
  float* upd    = (float*)alloc((size_t)B * L * H * 4);
  float* cmask  = (float*)alloc((size_t)B * L * 4);
  float* e_s    = (float*)alloc((size_t)B * H * 4);
  float* ecacc  = (float*)alloc((size_t)B * H * 4);
  float* sess   = (float*)alloc((size_t)B * H * 4);
  unsigned char* ET = (unsigned char*)alloc((size_t)B * L * L);
  s16x8* hbh = (s16x8*)alloc((size_t)B * 7 * 8 * 64 * 16);   // frag-linear
  s16x8* wnh = (s16x8*)alloc((size_t)B * 7 * 8 * 64 * 16);
  // lo-residual staging aliases P/upd (first written only inside the layer loop,
  // strictly after k_simws has consumed the staging buffers)
  s16x8* hbl = (s16x8*)P;
  s16x8* wnl = (s16x8*)upd;
  // emb bf16 hi/lo staging aliases S0/WS (dead after the last k_rowpass);
  // NT*8*64*16 B = 12.8 MB each <= 41 MB each
  s16x8* ebh = (s16x8*)S0;
  s16x8* ebl = (s16x8*)WS;

  k_embed<<<B * 7, 256, 0, stream>>>(seq, rev, emb, wnz, hidden, nrm,
                                     hbh, hbl, wnh, wnl);
  k_init<<<B, 512, 0, stream>>>(lens, hidden, ecacc, e_s);
  k_simws<<<B * 14, 256, 0, stream>>>(hbh, hbl, wnh, wnl, nrm, rev, clw, S0, WS);

  for (int i = 0; i < 2; ++i) {
    hipMemsetAsync(ET, 0, (size_t)B * L * L, stream);
    k_rowpass<<<B * 13, 256, 0, stream>>>(S0, WS, coff + (size_t)i * B * L * L,
                                          lens, P, ET);
    k_gather<<<B * L / 4, 512, 0, stream>>>(P, ET, hidden, cmask, upd);
    k_cnorm<<<B, 64, 0, stream>>>(cmask);
    k_ffn<<<B * L / 64, 256, 0, stream>>>(upd, w1, fb1, w2, fb2, lng, lnb, cmask);
    k_ecadd<<<B, 512, 0, stream>>>(upd, ecacc);
  }

  k_embconv<<<NT, 256, 0, stream>>>(emb, ebh, ebl);
  k_gate<<<B, 128, 0, stream>>>(ecacc, e_s, gw, sess, out);
  k_scores<<<dim3((NT + 15) / 16, 8), 256, 0, stream>>>(sess, ebh, ebl, out);
}

// Round 15
// 437.166 us; speedup vs baseline: 1.0600x; 1.0155x over previous
//
#include <hip/hip_runtime.h>
#include <cstdint>
#include <cstddef>

namespace {
constexpr int B = 256, L = 200, H = 128, V = 50000, TK = 20;
constexpr int NT = 1563;                   // ceil(V/32)
constexpr float NEGV = -1e10f;
}

using bf16x8 = __attribute__((ext_vector_type(8))) short;
using s16x8  = __attribute__((ext_vector_type(8))) short;
using f32x16 = __attribute__((ext_vector_type(16))) float;

__device__ inline unsigned short f2bf(float f) {
  unsigned int u = __float_as_uint(f);
  unsigned int r = (u + 0x7fffu + ((u >> 16) & 1u)) >> 16;   // RNE
  return (unsigned short)r;
}

// ---- 16-lane-group DPP reductions ------------------------------------------
#define DPP_QUAD_XOR1 0xB1
#define DPP_QUAD_XOR2 0x4E
#define DPP_ROW_HMIRR 0x141
#define DPP_ROW_MIRR  0x140

template <int CTRL>
__device__ inline unsigned dpp16_max_step(unsigned v) {
  unsigned t = (unsigned)__builtin_amdgcn_update_dpp(0, (int)v, CTRL, 0xF, 0xF, true);
  return v > t ? v : t;
}
__device__ inline unsigned grp16_max(unsigned v) {
  v = dpp16_max_step<DPP_QUAD_XOR1>(v);
  v = dpp16_max_step<DPP_QUAD_XOR2>(v);
  v = dpp16_max_step<DPP_ROW_HMIRR>(v);
  v = dpp16_max_step<DPP_ROW_MIRR>(v);
  return v;                                   // uniform within each 16-group
}
template <int CTRL>
__device__ inline float dpp16_add_step(float v) {
  int t = __builtin_amdgcn_update_dpp(0, __float_as_int(v), CTRL, 0xF, 0xF, true);
  return v + __int_as_float(t);
}
__device__ inline float grp16_sum(float v) {
  v = dpp16_add_step<DPP_QUAD_XOR1>(v);
  v = dpp16_add_step<DPP_QUAD_XOR2>(v);
  v = dpp16_add_step<DPP_ROW_HMIRR>(v);
  v = dpp16_add_step<DPP_ROW_MIRR>(v);
  return v;
}

__device__ inline unsigned f2key(float f) {        // order-preserving, bijective
  unsigned b = __float_as_uint(f);
  unsigned m = (unsigned)((int)b >> 31);
  return b ^ (m | 0x80000000u);
}
__device__ inline float key2f(unsigned u) {
  unsigned b = (u & 0x80000000u) ? (u & 0x7fffffffu) : ~u;
  return __uint_as_float(b);
}

// ---- embed + norm + frag-linear bf16 hi/lo staging --------------------------
__global__ __launch_bounds__(256) void k_embed(const int* __restrict__ seq,
                                               const int* __restrict__ rev,
                                               const float* __restrict__ emb,
                                               const float* __restrict__ wnoise,
                                               float* __restrict__ hidden,
                                               float* __restrict__ nrm,
                                               s16x8* __restrict__ hbh,
                                               s16x8* __restrict__ hbl,
                                               s16x8* __restrict__ wnh,
                                               s16x8* __restrict__ wnl) {
  int b = blockIdx.x / 7, lt = blockIdx.x % 7;
  int t = threadIdx.x;
  int r = t >> 3, c2 = t & 7;                 // row-in-tile, 16-elem h-chunk
  int l = lt * 32 + r;
  bool valid = l < L;
  float vv[16], wv[16];
  if (valid) {
    int row = b * L + l;
    int tok = seq[row];
    const float4* ep = (const float4*)&emb[(size_t)tok * H + c2 * 16];
    const float4* wp = (const float4*)&wnoise[(size_t)rev[row] * H + c2 * 16];
#pragma unroll
    for (int i = 0; i < 4; ++i) {
      float4 x = ep[i];
      vv[i * 4 + 0] = x.x; vv[i * 4 + 1] = x.y; vv[i * 4 + 2] = x.z; vv[i * 4 + 3] = x.w;
      float4 y = wp[i];
      wv[i * 4 + 0] = y.x; wv[i * 4 + 1] = y.y; wv[i * 4 + 2] = y.z; wv[i * 4 + 3] = y.w;
    }
  } else {
#pragma unroll
    for (int i = 0; i < 16; ++i) { vv[i] = 0.f; wv[i] = 0.f; }
  }
  if (valid) {
    int row = b * L + l;
#pragma unroll
    for (int i = 0; i < 4; ++i)
      *(float4*)&hidden[(size_t)row * H + c2 * 16 + i * 4] =
          make_float4(vv[i * 4], vv[i * 4 + 1], vv[i * 4 + 2], vv[i * 4 + 3]);
    float s = 0.f;
#pragma unroll
    for (int i = 0; i < 16; ++i) s += vv[i] * vv[i];
    s += __shfl_down(s, 4, 8);
    s += __shfl_down(s, 2, 8);
    s += __shfl_down(s, 1, 8);
    if (c2 == 0) nrm[row] = sqrtf(s);
  }
  s16x8 h0, h1, l0, l1, w0, w1, x0, x1;
#pragma unroll
  for (int i = 0; i < 8; ++i) {
    unsigned short hi = f2bf(vv[i]);
    h0[i] = (short)hi;
    l0[i] = (short)f2bf(vv[i] - __uint_as_float((unsigned)hi << 16));
    unsigned short wh = f2bf(wv[i]);
    w0[i] = (short)wh;
    x0[i] = (short)f2bf(wv[i] - __uint_as_float((unsigned)wh << 16));
  }
#pragma unroll
  for (int i = 0; i < 8; ++i) {
    unsigned short hi = f2bf(vv[8 + i]);
    h1[i] = (short)hi;
    l1[i] = (short)f2bf(vv[8 + i] - __uint_as_float((unsigned)hi << 16));
    unsigned short wh = f2bf(wv[8 + i]);
    w1[i] = (short)wh;
    x1[i] = (short)f2bf(wv[8 + i] - __uint_as_float((unsigned)wh << 16));
  }
  size_t fi0 = ((size_t)(b * 7 + lt) * 8 + c2) * 64 + r;   // kh=0
  size_t fi1 = fi0 + 32;                                   // kh=1
  hbh[fi0] = h0; hbh[fi1] = h1;
  hbl[fi0] = l0; hbl[fi1] = l1;
  wnh[fi0] = w0; wnh[fi1] = w1;
  wnl[fi0] = x0; wnl[fi1] = x1;
}

// ------------------------------------------ slen, zero_layer (into ecacc), e_s
__global__ __launch_bounds__(512) void k_init(const int* __restrict__ lengths,
                                              const float* __restrict__ hidden,
                                              float* __restrict__ ecacc,
                                              float* __restrict__ e_s) {
  int b = blockIdx.x, tid = threadIdx.x;
  __shared__ float part[4][128];
  __shared__ int wcnt[8];
  __shared__ int s_slen;
  int c = (tid < L && lengths[b * L + tid] > 0) ? 1 : 0;
  for (int o = 32; o > 0; o >>= 1) c += __shfl_down(c, o, 64);
  if ((tid & 63) == 0) wcnt[tid >> 6] = c;
  __syncthreads();
  if (tid == 0) {
    int s = 0;
#pragma unroll
    for (int i = 0; i < 8; ++i) s += wcnt[i];
    s_slen = s;
  }
  int h = tid & 127, seg = tid >> 7;
  float s = 0.f;
  for (int l = seg; l < L; l += 4) s += hidden[(size_t)(b * L + l) * H + h];
  part[seg][h] = s;
  __syncthreads();
  if (tid < 128) {
    float tot = part[0][h] + part[1][h] + part[2][h] + part[3][h];
    int slen = s_slen;
    ecacc[b * H + h] = tot / (float)slen;
    e_s[b * H + h] = hidden[(size_t)(b * L + slen - 1) * H + h];
  }
}

// ---- S0 = cosine sim (+diag), WS = softplus(hidden·wn), bf16x3 split MFMA ---
// one 32x32 mtile per wave; grid = 8 XCD * 32 b * 7 lt * 2 half
__global__ __launch_bounds__(256) void k_simws(const s16x8* __restrict__ hbh,
                                               const s16x8* __restrict__ hbl,
                                               const s16x8* __restrict__ wnh,
                                               const s16x8* __restrict__ wnl,
                                               const float* __restrict__ nrm,
                                               const int* __restrict__ rev,
                                               const float* __restrict__ cluster,
                                               float* __restrict__ S0,
                                               float* __restrict__ WS) {
  int orig = blockIdx.x;                     // 0..3583
  int xcd = orig & 7, slot = orig >> 3;      // slot 0..447
  int b = xcd * 32 + slot / 14;
  int rem = slot % 14;
  int lt = rem >> 1, half = rem & 1;
  int wid = threadIdx.x >> 6, lane = threadIdx.x & 63;
  int mt = half * 4 + wid;                   // 0..7
  if (mt > 6) return;                        // one idle wave in odd halves
  int lr = lane & 31, kh = lane >> 5;
  size_t abase = ((size_t)(b * 7 + lt) * 8) * 64 + lane;
  bf16x8 ah[8], al[8];
#pragma unroll
  for (int ks = 0; ks < 8; ++ks) {
    ah[ks] = (bf16x8)hbh[abase + ks * 64];
    al[ks] = (bf16x8)hbl[abase + ks * 64];
  }
  size_t bbase = ((size_t)(b * 7 + mt) * 8) * 64 + lane;
  f32x16 accs = {}, accw = {};
#pragma unroll
  for (int ks = 0; ks < 8; ++ks) {
    bf16x8 bhh = (bf16x8)hbh[bbase + ks * 64];
    bf16x8 bhl = (bf16x8)hbl[bbase + ks * 64];
    bf16x8 bwh = (bf16x8)wnh[bbase + ks * 64];
    bf16x8 bwl = (bf16x8)wnl[bbase + ks * 64];
    accs = __builtin_amdgcn_mfma_f32_32x32x16_bf16(ah[ks], bhh, accs, 0, 0, 0);
    accs = __builtin_amdgcn_mfma_f32_32x32x16_bf16(ah[ks], bhl, accs, 0, 0, 0);
    accs = __builtin_amdgcn_mfma_f32_32x32x16_bf16(al[ks], bhh, accs, 0, 0, 0);
    accw = __builtin_amdgcn_mfma_f32_32x32x16_bf16(ah[ks], bwh, accw, 0, 0, 0);
    accw = __builtin_amdgcn_mfma_f32_32x32x16_bf16(ah[ks], bwl, accw, 0, 0, 0);
    accw = __builtin_amdgcn_mfma_f32_32x32x16_bf16(al[ks], bwh, accw, 0, 0, 0);
  }
  int m = mt * 32 + lr;
  if (m < L) {
    float nm = nrm[b * L + m];
#pragma unroll
    for (int r = 0; r < 16; ++r) {
      int row = lt * 32 + (r & 3) + 8 * (r >> 2) + 4 * kh;
      if (row < L) {
        float nl = nrm[b * L + row];
        float s0 = accs[r] * __builtin_amdgcn_rcpf(nl * nm + 1e-6f);
        if (row == m) s0 += cluster[rev[b * L + row]];
        size_t o = (size_t)(b * L + row) * L + m;
        S0[o] = s0;
        float x = accw[r];
        WS[o] = (x > 1.f) ? x : __logf(1.f + __expf(x));
      }
    }
  }
}

// ------- BOTH layers per launch: S0/WS loaded once into regs; per layer:
// coff load, candidate-cached top-K (LDS key mirror, self-access), softmax.
__global__ __launch_bounds__(256) void k_rowpass2(const float* __restrict__ S0,
                                                  const float* __restrict__ WS,
                                                  const float* __restrict__ coff,
                                                  const int* __restrict__ lengths,
                                                  float* __restrict__ P1,
                                                  float* __restrict__ P2,
                                                  unsigned char* __restrict__ ET1,
                                                  unsigned char* __restrict__ ET2) {
  __shared__ unsigned klds[256 * 13];        // per-thread key mirror (self-access)
  int wid = threadIdx.x >> 6, lane = threadIdx.x & 63;
  int g = lane >> 4, q = lane & 15;
  int bb = blockIdx.x / 13, blk = blockIdx.x % 13;
  int l = blk * 16 + wid * 4 + g;
  bool lvalid = l < L;
  int lrow = bb * L + (lvalid ? l : 0);
  bool mask_l = lvalid && (lengths[lrow] > 0);
  size_t base = (size_t)lrow * L;
  int kbase = threadIdx.x * 13;
  // ---- load layer-invariant S0/WS once ----
  float s0v[13], wsv[13]; unsigned okm = 0;
#pragma unroll
  for (int j = 0; j < 13; ++j) {
    int m = q + 16 * j;
    bool ok = false; float a = 0.f, w = 0.f;
    if (mask_l && m < L) {
      ok = lengths[bb * L + m] > 0;
      if (ok) { a = S0[base + m]; w = WS[base + m]; }
    }
    s0v[j] = a; wsv[j] = w;
    okm |= ok ? (1u << j) : 0u;
  }
  for (int i = 0; i < 2; ++i) {
    const float* ci = coff + (size_t)i * B * L * L;
    float* P = i ? P2 : P1;
    unsigned char* ET = i ? ET2 : ET1;
    float val[13];
    unsigned h0 = 0, h1 = 0, h2 = 0; int j0 = 0, j1 = 0, j2 = 0;
#pragma unroll
    for (int j = 0; j < 13; ++j) {
      int m = q + 16 * j;
      bool ok = (okm >> j) & 1u;
      float v = 0.f;
      if (ok) v = s0v[j] + ci[base + m] * wsv[j];
      val[j] = v;
      unsigned k = ok ? f2key(v) : 0u;
      klds[kbase + j] = k;
      // per-lane sorted top-3 (strict > keeps lowest j on ties = lowest m)
      if (k > h0)      { h2 = h1; j2 = j1; h1 = h0; j1 = j0; h0 = k; j0 = j; }
      else if (k > h1) { h2 = h1; j2 = j1; h1 = k; j1 = j; }
      else if (k > h2) { h2 = k; j2 = j; }
    }
    unsigned cc = h0; int ccj = j0;          // current candidate
    int consumed = 0;
    unsigned Mu = 0u;
    for (int t = 0; t < TK; ++t) {
      unsigned gm = grp16_max(cc);
      if (t == 0) Mu = gm;
      if (__all(gm == 0u)) break;            // all 4 groups exhausted
      unsigned long long bal = __ballot(cc == gm && gm != 0u);
      unsigned long long mine = bal & (0xFFFFull << (g * 16));
      int owner = mine ? (int)__builtin_ctzll(mine) : -1;
      if (lane == owner) {                   // lowest lane of group (tie ok)
        int m = q + 16 * ccj;
        ET[((size_t)bb * L + m) * L + l] = 1;
        klds[kbase + ccj] = 0u;
        ++consumed;
        if (consumed == 1)      { cc = h1; ccj = j1; }
        else if (consumed == 2) { cc = h2; ccj = j2; }
        else {                               // rare exact rescan (own LDS keys)
          unsigned c2 = 0; int cj2 = 0;
#pragma unroll
          for (int j = 0; j < 13; ++j) {
            unsigned k2 = klds[kbase + j];
            if (k2 > c2) { c2 = k2; cj2 = j; }
          }
          cc = c2; ccj = cj2;
        }
      }
    }
    // softmax over the row (invalid entries contribute exactly 0)
    float M = key2f(Mu);
    float e[13]; float s = 0.f;
#pragma unroll
    for (int j = 0; j < 13; ++j) {
      float ev = ((okm >> j) & 1u) ? __expf(val[j] - M) : 0.f;
      e[j] = ev; s += ev;
    }
    s = grp16_sum(s);
    float inv = (s > 0.f) ? __builtin_amdgcn_rcpf(s) : 0.f;
    if (lvalid) {
#pragma unroll
      for (int j = 0; j < 13; ++j) {
        int m = q + 16 * j;
        if (m < L) P[base + m] = e[j] * inv;
      }
    }
  }
}

// ---- FUSED compact+update: ssm row -> cmask + LDS edge list -> gather -------
// 512 threads, 4 rows/block: waves 0-3 compact row 4*bid+wv (waves 4-7 wait);
// then all 512 threads gather (128 thr/row).
__global__ __launch_bounds__(512) void k_gather(const float* __restrict__ P,
                                                const unsigned char* __restrict__ ET,
                                                const float* __restrict__ hidden,
                                                float* __restrict__ cmask,
                                                float* __restrict__ upd) {
  __shared__ float wls[4][224];
  __shared__ unsigned char ils[4][224];
  __shared__ int s_cnt[4];
  int wv = threadIdx.x >> 6, lane = threadIdx.x & 63;
  if (wv < 4) {                              // only 4 compaction waves
    int rowW = blockIdx.x * 4 + wv;
    size_t baseW = (size_t)rowW * L;
    float w[4]; float s = 0.f;
#pragma unroll
    for (int j = 0; j < 4; ++j) {
      int m = lane + 64 * j;
      float ww = 0.f;
      if (m < L) ww = P[baseW + m] * (float)ET[baseW + m];
      w[j] = ww; s += ww;
    }
    float ssum = s;
    for (int off = 1; off < 64; off <<= 1) ssum += __shfl_xor(ssum, off, 64);
    if (lane == 0) cmask[rowW] = ssum;
    int pos_base = 0;
#pragma unroll
    for (int j = 0; j < 4; ++j) {
      bool nz = (w[j] != 0.f);
      unsigned long long mk = __ballot(nz);
      int rank = __popcll(mk & ((1ull << lane) - 1ull));
      if (nz) {
        int pos = pos_base + rank;
        ils[wv][pos] = (unsigned char)(lane + 64 * j);
        wls[wv][pos] = w[j];
      }
      pos_base += (int)__popcll(mk);
    }
    if (lane == 0) s_cnt[wv] = pos_base;
    int padEnd = ((pos_base + TK - 1) / TK) * TK;   // zero-pad to 20-multiple
    for (int p = pos_base + lane; p < padEnd; p += 64) {
      ils[wv][p] = 0; wls[wv][p] = 0.f;
    }
  }
  __syncthreads();
  int half = threadIdx.x >> 7;               // 0..3 -> row in block
  int h = threadIdx.x & 127;
  int row = blockIdx.x * 4 + half;
  int b = row / L;
  int n = s_cnt[half];
  float acc = 0.f;
  for (int e0 = 0; e0 < n; e0 += TK) {
    float w[TK]; int m[TK];
#pragma unroll
    for (int e = 0; e < TK; ++e) { w[e] = wls[half][e0 + e]; m[e] = ils[half][e0 + e]; }
    float hv[TK];
#pragma unroll
    for (int e = 0; e < TK; ++e)
      hv[e] = hidden[(size_t)(b * L + m[e]) * H + h];
#pragma unroll
    for (int e = 0; e < TK; ++e)
      acc += w[e] * hv[e];                   // padded entries are exact zeros
  }
  upd[(size_t)row * H + h] = acc;
}

// -------------------------------------------- cmask /= max(||cmask||_2, 1e-12)
__global__ __launch_bounds__(64) void k_cnorm(float* __restrict__ cmask) {
  int b = blockIdx.x, lane = threadIdx.x;   // 64 threads
  float v[4]; float s = 0.f;
#pragma unroll
  for (int j = 0; j < 4; ++j) {
    int l = lane + 64 * j;
    float x = (l < L) ? cmask[b * L + l] : 0.f;
    v[j] = x; s += x * x;
  }
  for (int off = 1; off < 64; off <<= 1) s += __shfl_xor(s, off, 64);
  float inv = 1.f / fmaxf(sqrtf(s), 1e-12f);
#pragma unroll
  for (int j = 0; j < 4; ++j) {
    int l = lane + 64 * j;
    if (l < L) cmask[b * L + l] = v[j] * inv;
  }
}

// ----- FFN + residual + LN via bf16x3 MFMA, weighted by cmask, in-place ------
__global__ __launch_bounds__(256) void k_ffn(float* __restrict__ upd,
                                             const float* __restrict__ W1,
                                             const float* __restrict__ b1,
                                             const float* __restrict__ W2,
                                             const float* __restrict__ b2,
                                             const float* __restrict__ g,
                                             const float* __restrict__ beta,
                                             const float* __restrict__ cmask) {
  constexpr int AS = 136;                            // short stride (16B-aligned rows)
  __shared__ __align__(16) char smem[4 * 64 * AS * 2];  // 69632 B
  short* ahs = (short*)smem;                         // A hi  [64][AS]
  short* als = ahs + 64 * AS;                        // A lo
  short* f1h = (short*)(smem + 2 * 64 * AS * 2);     // feed1 hi
  short* f1l = f1h + 64 * AS;
  float (*ps)[132] = (float (*)[132])smem;           // aliases A (dead after GEMM1)
  __shared__ float mus[64], rsd[64];
  int row0 = blockIdx.x * 64;
  int tid = threadIdx.x;
  int wid = tid >> 6, lane = tid & 63;
  int lr = lane & 31, kh = lane >> 5;
  int n0 = wid * 32;
  int n = n0 + lr;
  // ---- stage upd -> bf16 hi/lo LDS ----
#pragma unroll
  for (int it = 0; it < 8; ++it) {
    int f = it * 256 + tid;
    int r = f >> 5, c4 = (f & 31) * 4;
    float4 v = *(const float4*)&upd[(size_t)(row0 + r) * H + c4];
    float vv[4] = {v.x, v.y, v.z, v.w};
    unsigned short hh[4]; short ll[4];
#pragma unroll
    for (int q2 = 0; q2 < 4; ++q2) {
      hh[q2] = f2bf(vv[q2]);
      ll[q2] = (short)f2bf(vv[q2] - __uint_as_float((unsigned)hh[q2] << 16));
    }
    uint2 ph = make_uint2((unsigned)hh[0] | ((unsigned)hh[1] << 16),
                          (unsigned)hh[2] | ((unsigned)hh[3] << 16));
    uint2 pl = make_uint2((unsigned short)ll[0] | ((unsigned)(unsigned short)ll[1] << 16),
                          (unsigned short)ll[2] | ((unsigned)(unsigned short)ll[3] << 16));
    *(uint2*)&ahs[r * AS + c4] = ph;
    *(uint2*)&als[r * AS + c4] = pl;
  }
  __syncthreads();
  // ---- W1 fragments ----
  bf16x8 wfh[8], wfl[8];
#pragma unroll
  for (int ks = 0; ks < 8; ++ks) {
#pragma unroll
    for (int i = 0; i < 8; ++i) {
      float w = W1[(size_t)(ks * 16 + kh * 8 + i) * H + n];
      unsigned short hi = f2bf(w);
      wfh[ks][i] = (short)hi;
      wfl[ks][i] = (short)f2bf(w - __uint_as_float((unsigned)hi << 16));
    }
  }
  // ---- GEMM1: feed1 = relu(upd @ W1 + b1) ----
  f32x16 acc0, acc1;
  {
    float bv = b1[n];
#pragma unroll
    for (int r = 0; r < 16; ++r) { acc0[r] = bv; acc1[r] = bv; }
  }
#pragma unroll
  for (int ks = 0; ks < 8; ++ks) {
    bf16x8 xh0 = *(const bf16x8*)&ahs[(0 * 32 + lr) * AS + ks * 16 + kh * 8];
    bf16x8 xl0 = *(const bf16x8*)&als[(0 * 32 + lr) * AS + ks * 16 + kh * 8];
    bf16x8 xh1 = *(const bf16x8*)&ahs[(1 * 32 + lr) * AS + ks * 16 + kh * 8];
    bf16x8 xl1 = *(const bf16x8*)&als[(1 * 32 + lr) * AS + ks * 16 + kh * 8];
    acc0 = __builtin_amdgcn_mfma_f32_32x32x16_bf16(xh0, wfh[ks], acc0, 0, 0, 0);
    acc0 = __builtin_amdgcn_mfma_f32_32x32x16_bf16(xl0, wfh[ks], acc0, 0, 0, 0);
    acc0 = __builtin_amdgcn_mfma_f32_32x32x16_bf16(xh0, wfl[ks], acc0, 0, 0, 0);
    acc1 = __builtin_amdgcn_mfma_f32_32x32x16_bf16(xh1, wfh[ks], acc1, 0, 0, 0);
    acc1 = __builtin_amdgcn_mfma_f32_32x32x16_bf16(xl1, wfh[ks], acc1, 0, 0, 0);
    acc1 = __builtin_amdgcn_mfma_f32_32x32x16_bf16(xh1, wfl[ks], acc1, 0, 0, 0);
  }
  // relu -> f1 hi/lo LDS (C layout: row=(r&3)+8*(r>>2)+4*kh, col=n)
#pragma unroll
  for (int r = 0; r < 16; ++r) {
    int crow = (r & 3) + 8 * (r >> 2) + 4 * kh;
    float f0 = fmaxf(acc0[r], 0.f);
    unsigned short h0 = f2bf(f0);
    f1h[crow * AS + n] = (short)h0;
    f1l[crow * AS + n] = (short)f2bf(f0 - __uint_as_float((unsigned)h0 << 16));
    float f1v = fmaxf(acc1[r], 0.f);
    unsigned short h1 = f2bf(f1v);
    f1h[(32 + crow) * AS + n] = (short)h1;
    f1l[(32 + crow) * AS + n] = (short)f2bf(f1v - __uint_as_float((unsigned)h1 << 16));
  }
  __syncthreads();                                    // f1 complete; A region dead
  // ---- W2 fragments ----
#pragma unroll
  for (int ks = 0; ks < 8; ++ks) {
#pragma unroll
    for (int i = 0; i < 8; ++i) {
      float w = W2[(size_t)(ks * 16 + kh * 8 + i) * H + n];
      unsigned short hi = f2bf(w);
      wfh[ks][i] = (short)hi;
      wfl[ks][i] = (short)f2bf(w - __uint_as_float((unsigned)hi << 16));
    }
  }
  // ---- GEMM2: pre = feed1 @ W2 + b2 + upd ----
  {
    float bv = b2[n];
#pragma unroll
    for (int r = 0; r < 16; ++r) { acc0[r] = bv; acc1[r] = bv; }
  }
#pragma unroll
  for (int ks = 0; ks < 8; ++ks) {
    bf16x8 xh0 = *(const bf16x8*)&f1h[(0 * 32 + lr) * AS + ks * 16 + kh * 8];
    bf16x8 xl0 = *(const bf16x8*)&f1l[(0 * 32 + lr) * AS + ks * 16 + kh * 8];
    bf16x8 xh1 = *(const bf16x8*)&f1h[(1 * 32 + lr) * AS + ks * 16 + kh * 8];
    bf16x8 xl1 = *(const bf16x8*)&f1l[(1 * 32 + lr) * AS + ks * 16 + kh * 8];
    acc0 = __builtin_amdgcn_mfma_f32_32x32x16_bf16(xh0, wfh[ks], acc0, 0, 0, 0);
    acc0 = __builtin_amdgcn_mfma_f32_32x32x16_bf16(xl0, wfh[ks], acc0, 0, 0, 0);
    acc0 = __builtin_amdgcn_mfma_f32_32x32x16_bf16(xh0, wfl[ks], acc0, 0, 0, 0);
    acc1 = __builtin_amdgcn_mfma_f32_32x32x16_bf16(xh1, wfh[ks], acc1, 0, 0, 0);
    acc1 = __builtin_amdgcn_mfma_f32_32x32x16_bf16(xl1, wfh[ks], acc1, 0, 0, 0);
    acc1 = __builtin_amdgcn_mfma_f32_32x32x16_bf16(xh1, wfl[ks], acc1, 0, 0, 0);
  }
  // residual + write ps (pre) — ps aliases A region (dead since barrier)
#pragma unroll
  for (int r = 0; r < 16; ++r) {
    int crow = (r & 3) + 8 * (r >> 2) + 4 * kh;
    float p0 = acc0[r] + upd[(size_t)(row0 + crow) * H + n];
    float p1 = acc1[r] + upd[(size_t)(row0 + 32 + crow) * H + n];
    acc0[r] = p0; acc1[r] = p1;
    ps[crow][n] = p0;
    ps[32 + crow][n] = p1;
  }
  __syncthreads();
  // ---- LN stats: 4 threads per row ----
  {
    int r = tid >> 2, sub = tid & 3;
    float s = 0.f, sq = 0.f;
#pragma unroll
    for (int j = 0; j < 8; ++j) {
      float4 x = *(const float4*)&ps[r][sub * 32 + j * 4];
      s += x.x + x.y + x.z + x.w;
      sq += x.x * x.x + x.y * x.y + x.z * x.z + x.w * x.w;
    }
    s += __shfl_down(s, 2, 4);  s += __shfl_down(s, 1, 4);
    sq += __shfl_down(sq, 2, 4); sq += __shfl_down(sq, 1, 4);
    if (sub == 0) {
      float mu = s * (1.f / 128.f);
      float var = sq * (1.f / 128.f) - mu * mu;
      mus[r] = mu;
      rsd[r] = rsqrtf(var + 1e-5f);
    }
  }
  __syncthreads();
  // ---- normalize, scale by cmask, write ----
  {
    float gn = g[n], bn = beta[n];
#pragma unroll
    for (int r = 0; r < 16; ++r) {
      int crow = (r & 3) + 8 * (r >> 2) + 4 * kh;
      float o0 = ((acc0[r] - mus[crow]) * rsd[crow] * gn + bn) * cmask[row0 + crow];
      float o1 = ((acc1[r] - mus[32 + crow]) * rsd[32 + crow] * gn + bn) * cmask[row0 + 32 + crow];
      upd[(size_t)(row0 + crow) * H + n] = o0;
      upd[(size_t)(row0 + 32 + crow) * H + n] = o1;
    }
  }
}

// ---------------------------------------------- ecacc += sum_l (weighted feed2)
__global__ __launch_bounds__(512) void k_ecadd(const float* __restrict__ wf,
                                               float* __restrict__ ecacc) {
  int b = blockIdx.x, tid = threadIdx.x;
  __shared__ float part[4][128];
  int h = tid & 127, seg = tid >> 7;
  float s = 0.f;
  for (int l = seg; l < L; l += 4) s += wf[(size_t)(b * L + l) * H + h];
  part[seg][h] = s;
  __syncthreads();
  if (tid < 128)
    ecacc[b * H + h] += part[0][h] + part[1][h] + part[2][h] + part[3][h];
}

// ------------ emb fp32 -> frag-linear bf16 hi/lo (padded to NT 32-row tiles)
__global__ __launch_bounds__(256) void k_embconv(const float* __restrict__ emb,
                                                 s16x8* __restrict__ ebh,
                                                 s16x8* __restrict__ ebl) {
  int nt = blockIdx.x;
  int t = threadIdx.x;
  int r = t >> 3, c2 = t & 7;
  int n = nt * 32 + r;
  float vv[16];
  if (n < V) {
    const float4* ep = (const float4*)&emb[(size_t)n * H + c2 * 16];
#pragma unroll
    for (int i = 0; i < 4; ++i) {
      float4 x = ep[i];
      vv[i * 4 + 0] = x.x; vv[i * 4 + 1] = x.y; vv[i * 4 + 2] = x.z; vv[i * 4 + 3] = x.w;
    }
  } else {
#pragma unroll
    for (int i = 0; i < 16; ++i) vv[i] = 0.f;
  }
  s16x8 h0, h1, l0, l1;
#pragma unroll
  for (int i = 0; i < 8; ++i) {
    unsigned short hi = f2bf(vv[i]);
    h0[i] = (short)hi;
    l0[i] = (short)f2bf(vv[i] - __uint_as_float((unsigned)hi << 16));
    unsigned short hj = f2bf(vv[8 + i]);
    h1[i] = (short)hj;
    l1[i] = (short)f2bf(vv[8 + i] - __uint_as_float((unsigned)hj << 16));
  }
  size_t fi0 = ((size_t)nt * 8 + c2) * 64 + r;
  size_t fi1 = fi0 + 32;
  ebh[fi0] = h0; ebh[fi1] = h1;
  ebl[fi0] = l0; ebl[fi1] = l1;
}

// -------------------------------------------------------- gate -> sess, extras
__global__ __launch_bounds__(128) void k_gate(const float* __restrict__ ecacc,
                                              const float* __restrict__ e_s,
                                              const float* __restrict__ gw,
                                              float* __restrict__ sess,
                                              float* __restrict__ out) {
  __shared__ float cat[256];
  int b = blockIdx.x, h = threadIdx.x;
  float ec = ecacc[b * H + h] * (1.f / 3.f);
  float es = e_s[b * H + h];
  cat[h] = ec; cat[128 + h] = es;
  __syncthreads();
  float a = 0.f;
  for (int j = 0; j < 256; ++j) a = fmaf(cat[j], gw[(size_t)j * H + h], a);
  a = 1.f / (1.f + __expf(-a));
  sess[b * H + h] = a * ec + (1.f - a) * es;
  if (b == 0 && h == 0) out[(size_t)B * V] = 0.f;   // con_loss
}

// ---------- scores = sess @ emb^T via bf16x3 MFMA (frag-linear emb) ----------
__global__ __launch_bounds__(256) void k_scores(const float* __restrict__ sess,
                                                const s16x8* __restrict__ ebh,
                                                const s16x8* __restrict__ ebl,
                                                float* __restrict__ out) {
  int wid = threadIdx.x >> 6, lane = threadIdx.x & 63;
  int lr = lane & 31, kh = lane >> 5;
  int mt = blockIdx.y;
  int m = mt * 32 + lr;
  // A fragments from sess (fp32 -> bf16 hi/lo in registers; sess is L2-hot)
  bf16x8 ah[8], al[8];
#pragma unroll
  for (int ks = 0; ks < 8; ++ks) {
    const float* sp = &sess[(size_t)m * H + ks * 16 + kh * 8];
    float4 a = *(const float4*)sp;
    float4 c = *(const float4*)(sp + 4);
    float av[8] = {a.x, a.y, a.z, a.w, c.x, c.y, c.z, c.w};
#pragma unroll
    for (int i = 0; i < 8; ++i) {
      unsigned short hi = f2bf(av[i]);
      ah[ks][i] = (short)hi;
      al[ks][i] = (short)f2bf(av[i] - __uint_as_float((unsigned)hi << 16));
    }
  }
  int ntEnd = min(blockIdx.x * 16 + 16, NT);
  for (int nt = blockIdx.x * 16 + wid; nt < ntEnd; nt += 4) {
    size_t bbase = ((size_t)nt * 8) * 64 + lane;
    f32x16 acc = {};
#pragma unroll
    for (int ks = 0; ks < 8; ++ks) {
      bf16x8 bh = (bf16x8)ebh[bbase + ks * 64];
      bf16x8 bl = (bf16x8)ebl[bbase + ks * 64];
      acc = __builtin_amdgcn_mfma_f32_32x32x16_bf16(ah[ks], bh, acc, 0, 0, 0);
      acc = __builtin_amdgcn_mfma_f32_32x32x16_bf16(al[ks], bh, acc, 0, 0, 0);
      acc = __builtin_amdgcn_mfma_f32_32x32x16_bf16(ah[ks], bl, acc, 0, 0, 0);
    }
    int n = nt * 32 + lr;
    if (n < V) {
#pragma unroll
      for (int r = 0; r < 16; ++r) {
        int row = mt * 32 + (r & 3) + 8 * (r >> 2) + 4 * kh;
        out[(size_t)row * V + n] = acc[r];
      }
    }
  }
}

extern "C" void kernel_launch(void* const* d_in, const int* in_sizes, int n_in,
                              void* d_out, int out_size, void* d_ws, size_t ws_size,
                              hipStream_t stream) {
  const int*   seq  = (const int*)d_in[0];
  const int*   lens = (const int*)d_in[1];
  const int*   rev  = (const int*)d_in[2];
  const float* emb  = (const float*)d_in[3];
  const float* wnz  = (const float*)d_in[4];
  const float* clw  = (const float*)d_in[5];
  const float* w1   = (const float*)d_in[6];
  const float* fb1  = (const float*)d_in[7];
  const float* w2   = (const float*)d_in[8];
  const float* fb2  = (const float*)d_in[9];
  const float* lng  = (const float*)d_in[10];
  const float* lnb  = (const float*)d_in[11];
  const float* gw   = (const float*)d_in[12];
  const float* coff = (const float*)d_in[13];
  float* out = (float*)d_out;

  char* ws = (char*)d_ws;
  size_t off = 0;
  auto alloc = [&](size_t bytes) {
    void* p = ws + off;
    off += (bytes + 255) & ~(size_t)255;
    return p;
  };
  float* hidden = (float*)alloc((size_t)B * L * H * 4);
  float* nrm    = (float*)alloc((size_t)B * L * 4);
  float* S0     = (float*)alloc((size_t)B * L * L * 4);
  float* WS     = (float*)alloc((size_t)B * L * L * 4);
  float* P1     = (float*)alloc((size_t)B * L * L * 4);
  float* P2     = (float*)alloc((size_t)B * L * L * 4);
  float* upd    = (float*)alloc((size_t)B * L * H * 4);
  float* cmask  = (float*)alloc((size_t)B * L * 4);
  float* e_s    = (float*)alloc((size_t)B * H * 4);
  float* ecacc  = (float*)alloc((size_t)B * H * 4);
  float* sess   = (float*)alloc((size_t)B * H * 4);
  unsigned char* ET1 = (unsigned char*)alloc((size_t)B * L * L);
  unsigned char* ET2 = (unsigned char*)alloc((size_t)B * L * L);
  s16x8* hbh = (s16x8*)alloc((size_t)B * 7 * 8 * 64 * 16);   // frag-linear
  s16x8* wnh = (s16x8*)alloc((size_t)B * 7 * 8 * 64 * 16);
  // lo-residual staging aliases P1/upd (first written after simws consumed them)
  s16x8* hbl = (s16x8*)P1;
  s16x8* wnl = (s16x8*)upd;
  // emb bf16 hi/lo staging aliases S0/WS (dead after k_rowpass2);
  // embconv runs after the layer loop. 12.8 MB each <= 41 MB each.
  s16x8* ebh = (s16x8*)S0;
  s16x8* ebl = (s16x8*)WS;

  k_embed<<<B * 7, 256, 0, stream>>>(seq, rev, emb, wnz, hidden, nrm,
                                     hbh, hbl, wnh, wnl);
  k_init<<<B, 512, 0, stream>>>(lens, hidden, ecacc, e_s);
  k_simws<<<B * 14, 256, 0, stream>>>(hbh, hbl, wnh, wnl, nrm, rev, clw, S0, WS);

  hipMemsetAsync(ET1, 0, (size_t)B * L * L, stream);
  hipMemsetAsync(ET2, 0, (size_t)B * L * L, stream);
  k_rowpass2<<<B * 13, 256, 0, stream>>>(S0, WS, coff, lens, P1, P2, ET1, ET2);

  for (int i = 0; i < 2; ++i) {
    float* P = i ? P2 : P1;
    unsigned char* ET = i ? ET2 : ET1;
    k_gather<<<B * L / 4, 512, 0, stream>>>(P, ET, hidden, cmask, upd);
    k_cnorm<<<B, 64, 0, stream>>>(cmask);
    k_ffn<<<B * L / 64, 256, 0, stream>>>(upd, w1, fb1, w2, fb2, lng, lnb, cmask);
    k_ecadd<<<B, 512, 0, stream>>>(upd, ecacc);
  }

  k_embconv<<<NT, 256, 0, stream>>>(emb, ebh, ebl);
  k_gate<<<B, 128, 0, stream>>>(ecacc, e_s, gw, sess, out);
  k_scores<<<dim3((NT + 15) / 16, 8), 256, 0, stream>>>(sess, ebh, ebl, out);
}